// Round 15
// baseline (341.957 us; speedup 1.0000x reference)
//
#include <hip/hip_runtime.h>
#include <hip/hip_bf16.h>
#include <math.h>

#define DMODEL 2048
#define SEQ    2048
#define NH     32
#define NG     8
#define DH     64

typedef unsigned short u16;
typedef unsigned int u32;
using v8bf  = __attribute__((ext_vector_type(8))) __bf16;
using f32x4 = __attribute__((ext_vector_type(4))) float;

__device__ __forceinline__ float bf2f(u16 u) {
    unsigned int x = ((unsigned int)u) << 16;
    return __uint_as_float(x);
}
__device__ __forceinline__ u16 f2bf(float f) {
    unsigned int x = __float_as_uint(f);
    unsigned int r = (x + 0x7fffu + ((x >> 16) & 1u)) >> 16;
    return (u16)r;
}
// HW RNE convert (single v_cvt vs 4 int ops) — bit-identical to f2bf for normals.
__device__ __forceinline__ u16 f2bf_hw(float f) {
    __bf16 b = (__bf16)f;
    return __builtin_bit_cast(u16, b);
}
// Pack two floats to bf16x2 in a u32 (2 v_cvt + 1 v_lshl_or).
__device__ __forceinline__ u32 f2bf_pk(float lo, float hi) {
    return (u32)f2bf_hw(lo) | ((u32)f2bf_hw(hi) << 16);
}
__device__ __forceinline__ f32x4 mfma16(v8bf a, v8bf b, f32x4 c) {
    return __builtin_amdgcn_mfma_f32_16x16x32_bf16(a, b, c, 0, 0, 0);
}

#define LOG1E4_64 0.14391156509880297f
#define LOG2E     1.4426950408889634f

// ws layout (u16 element offsets). Weights TRANSPOSED [n][k].
#define C_HS   0u
#define C_WQ   8388608u
#define C_WK   12582912u
#define C_WV   13631488u
#define C_WO   14680064u
#define C_BO   18874368u
#define W_Q    18876416u   // [b,h][s][d]
#define W_K    27265024u   // [b,g][s][d]
#define W_V    29362176u   // [b,g][d][s]
#define W_CTX  31459328u   // transient RoPE table -> bf16 ctx

// ---------------------------------------------------------------------------
// Runtime input-dtype detection. nw = number of waves in the block.
// ---------------------------------------------------------------------------
__device__ __forceinline__ bool detect_is_f32(const u16* hsu, int tid, float* red, int nw)
{
    ushort4 a = *(const ushort4*)(hsu + tid * 8);
    ushort4 b = *(const ushort4*)(hsu + tid * 8 + 4);
    u16 vals[8] = {a.x, a.y, a.z, a.w, b.x, b.y, b.z, b.w};
    float mymax = 0.0f;
    #pragma unroll
    for (int e = 0; e < 8; ++e) {
        float av = fabsf(bf2f(vals[e]));
        if (!(av < 1.0e30f)) av = 1.0e30f;
        mymax = fmaxf(mymax, av);
    }
    #pragma unroll
    for (int off = 1; off < 64; off <<= 1)
        mymax = fmaxf(mymax, __shfl_xor(mymax, off, 64));
    if ((tid & 63) == 0) red[tid >> 6] = mymax;
    __syncthreads();
    float m = red[0];
    for (int i = 1; i < nw; ++i) m = fmaxf(m, red[i]);
    __syncthreads();
    return m > 1.0e6f;
}

// ---------------------------------------------------------------------------
// Prelude A: convert hs + bo to canonical bf16.
// ---------------------------------------------------------------------------
__global__ __launch_bounds__(256)
void conv_hs_bo(const void* __restrict__ hs, const void* __restrict__ bo,
                u16* __restrict__ canon)
{
    __shared__ float red[4];
    const int tid = threadIdx.x;
    const bool is_f32 = detect_is_f32((const u16*)hs, tid, red, 4);
    unsigned int g = (blockIdx.x * 256u + tid) * 8u;
    const void* src; unsigned int loc; u16* dst;
    if (g < 8388608u) { src = hs; loc = g;            dst = canon + C_HS + g; }
    else              { src = bo; loc = g - 8388608u; dst = canon + C_BO + loc; }

    ushort4 o0, o1;
    if (is_f32) {
        const float* f = (const float*)src + loc;
        float4 x = *(const float4*)f;
        float4 y = *(const float4*)(f + 4);
        o0.x = f2bf(x.x); o0.y = f2bf(x.y); o0.z = f2bf(x.z); o0.w = f2bf(x.w);
        o1.x = f2bf(y.x); o1.y = f2bf(y.y); o1.z = f2bf(y.z); o1.w = f2bf(y.w);
    } else {
        const u16* u = (const u16*)src + loc;
        o0 = *(const ushort4*)u;
        o1 = *(const ushort4*)(u + 4);
    }
    *(ushort4*)dst       = o0;
    *(ushort4*)(dst + 4) = o1;
}

// ---------------------------------------------------------------------------
// Prelude B (merged): all four weight transposes + RoPE table in ONE launch.
// blockIdx.z: 0=Wq 1=Wk 2=Wv 3=Wo (transpose-convert, K=2048), 4=rope table.
// Uniform per-block early exits (before any __syncthreads).
// ---------------------------------------------------------------------------
__global__ __launch_bounds__(256)
void transp_all(const void* __restrict__ Wq, const void* __restrict__ Wk,
                const void* __restrict__ Wv, const void* __restrict__ Wo,
                u16* __restrict__ canon, const u16* __restrict__ hs_orig,
                float* __restrict__ ropec, float* __restrict__ ropes)
{
    __shared__ float red[4];
    __shared__ u16 Ts[64][68];
    const int tid = threadIdx.x;
    const int z = blockIdx.z;

    if (z == 4) {   // RoPE table: 512 blocks worth of work
        int bid = blockIdx.y * 32 + blockIdx.x;
        if (bid >= 512) return;
        int idx = bid * 256 + tid;
        int sq = idx >> 6, d = idx & 63;
        float freq = expf(-(float)(d & ~1) * LOG1E4_64);
        float sn, cs;
        sincosf((float)sq * freq, &sn, &cs);
        ropec[idx] = cs; ropes[idx] = sn;
        return;
    }

    const void* W; u16* dst; int N;
    if (z == 0)      { W = Wq; dst = canon + C_WQ; N = 2048; }
    else if (z == 1) { W = Wk; dst = canon + C_WK; N = 512;  }
    else if (z == 2) { W = Wv; dst = canon + C_WV; N = 512;  }
    else             { W = Wo; dst = canon + C_WO; N = 2048; }
    const int n0 = blockIdx.x * 64, k0 = blockIdx.y * 64;
    if (n0 >= N) return;
    const int K = 2048;

    const bool is_f32 = detect_is_f32(hs_orig, tid, red, 4);

    #pragma unroll
    for (int it = 0; it < 4; ++it) {
        int e  = tid + it * 256;
        int kr = e >> 4, n4 = (e & 15) << 2;
        if (is_f32) {
            const float* s = (const float*)W + (size_t)(k0 + kr) * N + n0 + n4;
            float4 x = *(const float4*)s;
            Ts[n4+0][kr] = f2bf(x.x); Ts[n4+1][kr] = f2bf(x.y);
            Ts[n4+2][kr] = f2bf(x.z); Ts[n4+3][kr] = f2bf(x.w);
        } else {
            ushort4 u = *(const ushort4*)((const u16*)W + (size_t)(k0 + kr) * N + n0 + n4);
            Ts[n4+0][kr] = u.x; Ts[n4+1][kr] = u.y;
            Ts[n4+2][kr] = u.z; Ts[n4+3][kr] = u.w;
        }
    }
    __syncthreads();
    #pragma unroll
    for (int it = 0; it < 4; ++it) {
        int e  = tid + it * 256;
        int nr = e >> 4, k4 = (e & 15) << 2;
        ushort4 u;
        u.x = Ts[nr][k4+0]; u.y = Ts[nr][k4+1];
        u.z = Ts[nr][k4+2]; u.w = Ts[nr][k4+3];
        *(ushort4*)(dst + (size_t)(n0 + nr) * K + k0 + k4) = u;
    }
}

// ---------------------------------------------------------------------------
// Kernel 1: QKV projection (MFMA) + RoPE epilogue. 128x128 tile, BK=64,
// 512 threads = 8 waves (2x4), 64x32 per wave, demand<128 register contract
// (R4/R5/R12: acc[4][4]@256thr spills regardless of launch-bounds hints).
// Reg-staged [128][72] pad + cross-barrier prefetch (R10: gload_lds worse).
// R15: XCD-aware block swizzle (T1) — default dispatch round-robins
// consecutive blocks (same B-panel, different rows) across 8 XCDs, so every
// 512KB B-panel lands in all 8 private L2s (FETCH 67MB vs ~30MB compulsory).
// Bijective remap (768%8==0): each XCD gets contiguous rows over 3 B-panels
// -> B L2-resident per XCD, loads at L2 latency instead of L3/HBM.
// ---------------------------------------------------------------------------
__global__ __launch_bounds__(512, 4) __attribute__((amdgpu_waves_per_eu(4, 4)))
void gemm_qkv(const u16* __restrict__ hs, const u16* __restrict__ wqt,
              const u16* __restrict__ wkt, const u16* __restrict__ wvt,
              const float* __restrict__ ropec, const float* __restrict__ ropes,
              u16* __restrict__ qws, u16* __restrict__ kws, u16* __restrict__ vws)
{
    __shared__ __align__(16) u16 As[128][72];
    __shared__ __align__(16) u16 Bs[128][72];
    const int tid = threadIdx.x;
    const int w = tid >> 6, lane = tid & 63;
    const int l15 = lane & 15, quad = lane >> 4;
    const int wr = (w >> 2) * 64, wc = (w & 3) * 32;

    // XCD swizzle: nwg = 32*24 = 768, 96 per XCD (bijective: 768 % 8 == 0)
    const int bid = (int)(blockIdx.y * 32 + blockIdx.x);
    const int swz = (bid & 7) * 96 + (bid >> 3);
    const int row0 = (swz & 31) * 128;
    const int n0   = (swz >> 5) * 128;

    const u16* Wt; int nb, mode;
    if (n0 < 2048)      { Wt = wqt; nb = n0;        mode = 0; }
    else if (n0 < 2560) { Wt = wkt; nb = n0 - 2048; mode = 1; }
    else                { Wt = wvt; nb = n0 - 2560; mode = 2; }

    const int r0 = tid >> 3, c0 = (tid & 7) * 8;
    const u16* arow = hs + (size_t)(row0 + r0) * DMODEL + c0;
    const u16* brow = Wt + (size_t)(nb   + r0) * DMODEL + c0;

    f32x4 acc[4][2];
    #pragma unroll
    for (int mt = 0; mt < 4; ++mt)
        #pragma unroll
        for (int nt = 0; nt < 2; ++nt)
            acc[mt][nt] = (f32x4){0.f, 0.f, 0.f, 0.f};

    uint4 ra0, ra1, rb0, rb1;
#define LOADG(k0_) do {                                                       \
    ra0 = *(const uint4*)(arow + (k0_));                                      \
    ra1 = *(const uint4*)(arow + (size_t)64 * DMODEL + (k0_));                \
    rb0 = *(const uint4*)(brow + (k0_));                                      \
    rb1 = *(const uint4*)(brow + (size_t)64 * DMODEL + (k0_));                \
} while (0)
#define STORELDS() do {                                                       \
    *(uint4*)&As[r0][c0]      = ra0;                                          \
    *(uint4*)&As[r0 + 64][c0] = ra1;                                          \
    *(uint4*)&Bs[r0][c0]      = rb0;                                          \
    *(uint4*)&Bs[r0 + 64][c0] = rb1;                                          \
} while (0)

    LOADG(0);
    for (int k0 = 0; k0 < DMODEL; k0 += 64) {
        STORELDS();
        __syncthreads();
        if (k0 + 64 < DMODEL) LOADG(k0 + 64);
        #pragma unroll
        for (int ks = 0; ks < 2; ++ks) {
            v8bf a[4], b[2];
            #pragma unroll
            for (int mt = 0; mt < 4; ++mt)
                a[mt] = *(const v8bf*)&As[wr + 16*mt + l15][ks*32 + quad*8];
            #pragma unroll
            for (int nt = 0; nt < 2; ++nt)
                b[nt] = *(const v8bf*)&Bs[wc + 16*nt + l15][ks*32 + quad*8];
            #pragma unroll
            for (int mt = 0; mt < 4; ++mt)
                #pragma unroll
                for (int nt = 0; nt < 2; ++nt)
                    acc[mt][nt] = mfma16(a[mt], b[nt], acc[mt][nt]);
        }
        __syncthreads();
    }
#undef LOADG
#undef STORELDS

    #pragma unroll
    for (int mt = 0; mt < 4; ++mt) {
        #pragma unroll
        for (int nt = 0; nt < 2; ++nt) {
            int col  = n0 + wc + 16*nt + l15;
            int dcol = col & 63;
            #pragma unroll
            for (int reg = 0; reg < 4; ++reg) {
                int row = row0 + wr + 16*mt + quad*4 + reg;
                int b = row >> 11, s = row & (SEQ - 1);
                float val = acc[mt][nt][reg];
                if (mode < 2) {   // RoPE (pairs sit in adjacent lanes)
                    float c2 = ropec[(s << 6) + dcol];
                    float s2 = ropes[(s << 6) + dcol];
                    float partner = __shfl_xor(val, 1, 64);
                    val = (dcol & 1) ? (val * c2 + partner * s2)
                                     : (val * c2 - partner * s2);
                }
                if (mode == 0) {
                    int h = col >> 6;
                    qws[((size_t)((b*NH + h) * SEQ + s)) * DH + dcol] = f2bf_hw(val);
                } else if (mode == 1) {
                    int g = (col - 2048) >> 6;
                    kws[((size_t)((b*NG + g) * SEQ + s)) * DH + dcol] = f2bf_hw(val);
                } else {
                    int g = (col - 2560) >> 6;
                    vws[((size_t)((b*NG + g) * DH + dcol)) * SEQ + s] = f2bf_hw(val);
                }
            }
        }
    }
}

// ---------------------------------------------------------------------------
// Kernel 2: flash attention (R14-verified, unchanged). Two q-tiles per
// block; K/V staged once into LDS, 2-phase lockstep with next-tile prefetch;
// swapped QK^T (mfma(K,Q)); packed P-store; causal mask s_local > 16w+l15;
// l via ones-fragment MFMA appended to PV.
// ---------------------------------------------------------------------------
__global__ __launch_bounds__(256, 4)
void attn(const u16* __restrict__ qws, const u16* __restrict__ kws,
          const u16* __restrict__ vws, u16* __restrict__ ctx)
{
    __shared__ __align__(16) u16 Ks[64][72];      // K tile [s_local][d]
    __shared__ __align__(16) u16 Vs[64][72];      // V tile [d][s_local]
    __shared__ __align__(16) u16 Ps[4][16][72];   // wave-private P [q][s]
    const int tid = threadIdx.x;
    const int w = tid >> 6, lane = tid & 63;
    const int l15 = lane & 15, quad = lane >> 4;
    const int sr = tid >> 3;          // staging row 0..31 (+32 second pass)
    const int sc = (tid & 7) * 8;     // staging col (u16 units, 16B chunks)

    const int h = blockIdx.y, b = blockIdx.z;
    const int g = h >> 2;

    const float slope = exp2f(-0.25f * (float)(h + 1));
    const u16* kbase  = kws + (size_t)(b*NG + g) * SEQ * DH;
    const u16* vtbase = vws + (size_t)(b*NG + g) * DH * SEQ;   // [d][s]
    const u16* qhead  = qws + (size_t)(b*NH + h) * SEQ * DH;

    const float Ac = 0.125f * (LOG2E / 15.0f);
    const float Bc = -slope * 0.125f * (LOG2E / 15.0f);
    const float C3 = -60.0f * LOG2E;
    // swapped bias: q_local = 16w + l15, s_local = 16mt + 4quad + rg
    float bdw[4][4];
    #pragma unroll
    for (int mt = 0; mt < 4; ++mt)
        #pragma unroll
        for (int reg = 0; reg < 4; ++reg)
            bdw[mt][reg] = Bc * (float)((16*w + l15) - (16*mt + 4*quad + reg));

    // all-ones B fragment for the l-row MFMA
    v8bf vones;
    #pragma unroll
    for (int j = 0; j < 8; ++j) vones[j] = (__bf16)1.0f;

    uint4 rk0, rk1, rv0, rv1;   // in-flight staging registers (one K/V tile)

#define LOADG(kt_) do {                                                       \
    const u16* kp_ = kbase + (size_t)(kt_) * (64 * DH);                       \
    rk0 = *(const uint4*)(kp_ + sr * DH + sc);                                \
    rk1 = *(const uint4*)(kp_ + (sr + 32) * DH + sc);                         \
    const u16* vp_ = vtbase + (size_t)(kt_) * 64;                             \
    rv0 = *(const uint4*)(vp_ + (size_t)sr * SEQ + sc);                       \
    rv1 = *(const uint4*)(vp_ + (size_t)(sr + 32) * SEQ + sc);                \
} while (0)

#define STORELDS() do {                                                       \
    *(uint4*)&Ks[sr][sc]      = rk0;                                          \
    *(uint4*)&Ks[sr + 32][sc] = rk1;                                          \
    *(uint4*)&Vs[sr][sc]      = rv0;                                          \
    *(uint4*)&Vs[sr + 32][sc] = rv1;                                          \
} while (0)

#define COMPUTE(kt_, DIAGC) do {                                              \
    f32x4 sacc_[4];                                                           \
    _Pragma("unroll")                                                         \
    for (int mt_ = 0; mt_ < 4; ++mt_) sacc_[mt_] = (f32x4){0.f,0.f,0.f,0.f};  \
    _Pragma("unroll")                                                         \
    for (int ks_ = 0; ks_ < 2; ++ks_)                                         \
        _Pragma("unroll")                                                     \
        for (int mt_ = 0; mt_ < 4; ++mt_) {                                   \
            v8bf kf_ = *(const v8bf*)&Ks[16*mt_ + l15][ks_*32 + quad*8];      \
            sacc_[mt_] = mfma16(kf_, qa[ks_], sacc_[mt_]);                    \
        }                                                                     \
    const float tb_ = Bc * (float)(q0 - (kt_) * 64);                          \
    _Pragma("unroll")                                                         \
    for (int mt_ = 0; mt_ < 4; ++mt_) {                                       \
        float pv_[4];                                                         \
        _Pragma("unroll")                                                     \
        for (int rg_ = 0; rg_ < 4; ++rg_) {                                   \
            float arg_ = fmaf(sacc_[mt_][rg_], Ac, bdw[mt_][rg_] + tb_);      \
            float wv_  = __builtin_amdgcn_exp2f(arg_);                        \
            float rr_  = __builtin_amdgcn_rcpf(wv_ + 1.0f);                   \
            float p_   = __builtin_amdgcn_exp2f(rr_ * C3);                    \
            if (DIAGC && (16*mt_ + 4*quad + rg_) > (16*w + l15)) p_ = 0.0f;   \
            pv_[rg_] = p_;                                                    \
        }                                                                     \
        uint2 pk_;                                                            \
        pk_.x = f2bf_pk(pv_[0], pv_[1]);                                      \
        pk_.y = f2bf_pk(pv_[2], pv_[3]);                                      \
        *(uint2*)&Ps[w][l15][16*mt_ + quad*4] = pk_;                          \
    }                                                                         \
    _Pragma("unroll")                                                         \
    for (int ks_ = 0; ks_ < 2; ++ks_) {                                       \
        v8bf pa_ = *(const v8bf*)&Ps[w][l15][ks_*32 + quad*8];                \
        _Pragma("unroll")                                                     \
        for (int dt_ = 0; dt_ < 4; ++dt_) {                                   \
            v8bf vf_ = *(const v8bf*)&Vs[16*dt_ + l15][ks_*32 + quad*8];      \
            o[dt_] = mfma16(pa_, vf_, o[dt_]);                                \
        }                                                                     \
        lacc = mfma16(pa_, vones, lacc);                                      \
    }                                                                         \
} while (0)

    #pragma unroll 1
    for (int half = 0; half < 2; ++half) {
        const int qt = half ? 31 - (int)blockIdx.x : (int)blockIdx.x;
        const int q0 = qt * 64;

        // Q frags in registers: rows q0+16w+l15 (valid as A or B operand)
        const u16* qrow = qhead + (size_t)(q0 + 16*w + l15) * DH;
        v8bf qa[2];
        qa[0] = *(const v8bf*)(qrow + 0*32 + quad*8);
        qa[1] = *(const v8bf*)(qrow + 1*32 + quad*8);

        f32x4 o[4];
        #pragma unroll
        for (int dt = 0; dt < 4; ++dt) o[dt] = (f32x4){0.f, 0.f, 0.f, 0.f};
        f32x4 lacc = (f32x4){0.f, 0.f, 0.f, 0.f};   // l[q=quad*4+reg], any col

        LOADG(0);
        for (int kt = 0; kt < qt; ++kt) {
            STORELDS();
            __syncthreads();
            LOADG(kt + 1);          // prefetch next tile while computing this one
            COMPUTE(kt, 0);
            __syncthreads();
        }
        STORELDS();                 // diag tile
        __syncthreads();
        COMPUTE(qt, 1);
        __syncthreads();

        // epilogue: l already in lacc[reg] (ones-MFMA) — no shuffles needed
        #pragma unroll
        for (int reg = 0; reg < 4; ++reg) {
            float linv = __builtin_amdgcn_rcpf(lacc[reg]);
            int s = q0 + 16*w + quad*4 + reg;
            u16* crow = ctx + (size_t)(b*SEQ + s) * DMODEL + h*64 + l15;
            #pragma unroll
            for (int dt = 0; dt < 4; ++dt)
                crow[16*dt] = f2bf_hw(o[dt][reg] * linv);
        }
    }
#undef LOADG
#undef STORELDS
#undef COMPUTE
}

// ---------------------------------------------------------------------------
// Kernel 3: out = ctx @ Wo + bo. Same reg-staged 512-thread structure as
// gemm_qkv + XCD swizzle (512 blocks, 64/XCD, bijective). LAUNCH WITH 512.
// ---------------------------------------------------------------------------
__global__ __launch_bounds__(512, 4) __attribute__((amdgpu_waves_per_eu(4, 4)))
void oproj(const u16* __restrict__ ctx, const u16* __restrict__ wot,
           const u16* __restrict__ bo, const u16* __restrict__ hs_orig,
           void* __restrict__ outp)
{
    __shared__ float red[8];
    __shared__ __align__(16) u16 As[128][72];
    __shared__ __align__(16) u16 Bs[128][72];
    const int tid = threadIdx.x;
    const bool is_f32 = detect_is_f32(hs_orig, tid, red, 8);
    const int w = tid >> 6, lane = tid & 63;
    const int l15 = lane & 15, quad = lane >> 4;
    const int wr = (w >> 2) * 64, wc = (w & 3) * 32;

    // XCD swizzle: nwg = 32*16 = 512, 64 per XCD (bijective)
    const int bid = (int)(blockIdx.y * 32 + blockIdx.x);
    const int swz = (bid & 7) * 64 + (bid >> 3);
    const int row0 = (swz & 31) * 128;
    const int n0   = (swz >> 5) * 128;

    const int r0 = tid >> 3, c0 = (tid & 7) * 8;
    const u16* arow = ctx + (size_t)(row0 + r0) * DMODEL + c0;
    const u16* brow = wot + (size_t)(n0   + r0) * DMODEL + c0;

    f32x4 acc[4][2];
    #pragma unroll
    for (int mt = 0; mt < 4; ++mt)
        #pragma unroll
        for (int nt = 0; nt < 2; ++nt)
            acc[mt][nt] = (f32x4){0.f, 0.f, 0.f, 0.f};

    uint4 ra0, ra1, rb0, rb1;
#define LOADG(k0_) do {                                                       \
    ra0 = *(const uint4*)(arow + (k0_));                                      \
    ra1 = *(const uint4*)(arow + (size_t)64 * DMODEL + (k0_));                \
    rb0 = *(const uint4*)(brow + (k0_));                                      \
    rb1 = *(const uint4*)(brow + (size_t)64 * DMODEL + (k0_));                \
} while (0)
#define STORELDS() do {                                                       \
    *(uint4*)&As[r0][c0]      = ra0;                                          \
    *(uint4*)&As[r0 + 64][c0] = ra1;                                          \
    *(uint4*)&Bs[r0][c0]      = rb0;                                          \
    *(uint4*)&Bs[r0 + 64][c0] = rb1;                                          \
} while (0)

    LOADG(0);
    for (int k0 = 0; k0 < DMODEL; k0 += 64) {
        STORELDS();
        __syncthreads();
        if (k0 + 64 < DMODEL) LOADG(k0 + 64);
        #pragma unroll
        for (int ks = 0; ks < 2; ++ks) {
            v8bf a[4], b[2];
            #pragma unroll
            for (int mt = 0; mt < 4; ++mt)
                a[mt] = *(const v8bf*)&As[wr + 16*mt + l15][ks*32 + quad*8];
            #pragma unroll
            for (int nt = 0; nt < 2; ++nt)
                b[nt] = *(const v8bf*)&Bs[wc + 16*nt + l15][ks*32 + quad*8];
            #pragma unroll
            for (int mt = 0; mt < 4; ++mt)
                #pragma unroll
                for (int nt = 0; nt < 2; ++nt)
                    acc[mt][nt] = mfma16(a[mt], b[nt], acc[mt][nt]);
        }
        __syncthreads();
    }
#undef LOADG
#undef STORELDS

    #pragma unroll
    for (int mt = 0; mt < 4; ++mt) {
        #pragma unroll
        for (int nt = 0; nt < 2; ++nt) {
            int col = n0 + wc + 16*nt + l15;
            float bias = bf2f(bo[col]);
            #pragma unroll
            for (int reg = 0; reg < 4; ++reg) {
                int row = row0 + wr + 16*mt + quad*4 + reg;
                float val = acc[mt][nt][reg] + bias;
                if (is_f32) ((float*)outp)[(size_t)row * DMODEL + col] = val;
                else        ((u16*)outp)[(size_t)row * DMODEL + col]   = f2bf(val);
            }
        }
    }
}

extern "C" void kernel_launch(void* const* d_in, const int* in_sizes, int n_in,
                              void* d_out, int out_size, void* d_ws, size_t ws_size,
                              hipStream_t stream) {
    u16* ws = (u16*)d_ws;
    u16* canon = ws;
    u16* qws = ws + W_Q;
    u16* kws = ws + W_K;
    u16* vws = ws + W_V;
    u16* ctxp = ws + W_CTX;
    float* ropec = (float*)(ws + W_CTX);          // transient (dead before attn writes ctx)
    float* ropes = ropec + SEQ * DH;
    const u16* hs_raw = (const u16*)d_in[0];

    conv_hs_bo<<<dim3(4097), 256, 0, stream>>>(d_in[0], d_in[5], canon);
    transp_all<<<dim3(32, 32, 5), 256, 0, stream>>>(d_in[1], d_in[2], d_in[3],
        d_in[4], canon, hs_raw, ropec, ropes);
    gemm_qkv<<<dim3(32, 24), 512, 0, stream>>>(canon + C_HS, canon + C_WQ,
        canon + C_WK, canon + C_WV, ropec, ropes, qws, kws, vws);
    attn<<<dim3(16, NH, 2), 256, 0, stream>>>(qws, kws, vws, ctxp);
    oproj<<<dim3(32, 16), 512, 0, stream>>>(ctxp, canon + C_WO, canon + C_BO, hs_raw, d_out);
}

// Round 16
// 338.206 us; speedup vs baseline: 1.0111x; 1.0111x over previous
//
#include <hip/hip_runtime.h>
#include <hip/hip_bf16.h>
#include <math.h>

#define DMODEL 2048
#define SEQ    2048
#define NH     32
#define NG     8
#define DH     64

typedef unsigned short u16;
typedef unsigned int u32;
using v8bf  = __attribute__((ext_vector_type(8))) __bf16;
using f32x4 = __attribute__((ext_vector_type(4))) float;

__device__ __forceinline__ float bf2f(u16 u) {
    unsigned int x = ((unsigned int)u) << 16;
    return __uint_as_float(x);
}
__device__ __forceinline__ u16 f2bf(float f) {
    unsigned int x = __float_as_uint(f);
    unsigned int r = (x + 0x7fffu + ((x >> 16) & 1u)) >> 16;
    return (u16)r;
}
// HW RNE convert (single v_cvt vs 4 int ops) — bit-identical to f2bf for normals.
__device__ __forceinline__ u16 f2bf_hw(float f) {
    __bf16 b = (__bf16)f;
    return __builtin_bit_cast(u16, b);
}
// Pack two floats to bf16x2 in a u32 (2 v_cvt + 1 v_lshl_or).
__device__ __forceinline__ u32 f2bf_pk(float lo, float hi) {
    return (u32)f2bf_hw(lo) | ((u32)f2bf_hw(hi) << 16);
}
__device__ __forceinline__ f32x4 mfma16(v8bf a, v8bf b, f32x4 c) {
    return __builtin_amdgcn_mfma_f32_16x16x32_bf16(a, b, c, 0, 0, 0);
}

#define LOG1E4_64 0.14391156509880297f
#define LOG2E     1.4426950408889634f

// ws layout (u16 element offsets). Weights TRANSPOSED [n][k].
#define C_HS   0u
#define C_WQ   8388608u
#define C_WK   12582912u
#define C_WV   13631488u
#define C_WO   14680064u
#define C_BO   18874368u
#define W_Q    18876416u   // [b,h][s][d]
#define W_K    27265024u   // [b,g][s][d]
#define W_V    29362176u   // [b,g][d][s]
#define W_CTX  31459328u   // transient RoPE table -> bf16 ctx

// ---------------------------------------------------------------------------
// Runtime input-dtype detection. nw = number of waves in the block.
// ---------------------------------------------------------------------------
__device__ __forceinline__ bool detect_is_f32(const u16* hsu, int tid, float* red, int nw)
{
    ushort4 a = *(const ushort4*)(hsu + tid * 8);
    ushort4 b = *(const ushort4*)(hsu + tid * 8 + 4);
    u16 vals[8] = {a.x, a.y, a.z, a.w, b.x, b.y, b.z, b.w};
    float mymax = 0.0f;
    #pragma unroll
    for (int e = 0; e < 8; ++e) {
        float av = fabsf(bf2f(vals[e]));
        if (!(av < 1.0e30f)) av = 1.0e30f;
        mymax = fmaxf(mymax, av);
    }
    #pragma unroll
    for (int off = 1; off < 64; off <<= 1)
        mymax = fmaxf(mymax, __shfl_xor(mymax, off, 64));
    if ((tid & 63) == 0) red[tid >> 6] = mymax;
    __syncthreads();
    float m = red[0];
    for (int i = 1; i < nw; ++i) m = fmaxf(m, red[i]);
    __syncthreads();
    return m > 1.0e6f;
}

// ---------------------------------------------------------------------------
// Prelude A: convert hs + bo to canonical bf16.
// ---------------------------------------------------------------------------
__global__ __launch_bounds__(256)
void conv_hs_bo(const void* __restrict__ hs, const void* __restrict__ bo,
                u16* __restrict__ canon)
{
    __shared__ float red[4];
    const int tid = threadIdx.x;
    const bool is_f32 = detect_is_f32((const u16*)hs, tid, red, 4);
    unsigned int g = (blockIdx.x * 256u + tid) * 8u;
    const void* src; unsigned int loc; u16* dst;
    if (g < 8388608u) { src = hs; loc = g;            dst = canon + C_HS + g; }
    else              { src = bo; loc = g - 8388608u; dst = canon + C_BO + loc; }

    ushort4 o0, o1;
    if (is_f32) {
        const float* f = (const float*)src + loc;
        float4 x = *(const float4*)f;
        float4 y = *(const float4*)(f + 4);
        o0.x = f2bf(x.x); o0.y = f2bf(x.y); o0.z = f2bf(x.z); o0.w = f2bf(x.w);
        o1.x = f2bf(y.x); o1.y = f2bf(y.y); o1.z = f2bf(y.z); o1.w = f2bf(y.w);
    } else {
        const u16* u = (const u16*)src + loc;
        o0 = *(const ushort4*)u;
        o1 = *(const ushort4*)(u + 4);
    }
    *(ushort4*)dst       = o0;
    *(ushort4*)(dst + 4) = o1;
}

// ---------------------------------------------------------------------------
// Prelude B (merged): all four weight transposes + RoPE table in ONE launch.
// blockIdx.z: 0=Wq 1=Wk 2=Wv 3=Wo (transpose-convert, K=2048), 4=rope table.
// Uniform per-block early exits (before any __syncthreads).
// ---------------------------------------------------------------------------
__global__ __launch_bounds__(256)
void transp_all(const void* __restrict__ Wq, const void* __restrict__ Wk,
                const void* __restrict__ Wv, const void* __restrict__ Wo,
                u16* __restrict__ canon, const u16* __restrict__ hs_orig,
                float* __restrict__ ropec, float* __restrict__ ropes)
{
    __shared__ float red[4];
    __shared__ u16 Ts[64][68];
    const int tid = threadIdx.x;
    const int z = blockIdx.z;

    if (z == 4) {   // RoPE table: 512 blocks worth of work
        int bid = blockIdx.y * 32 + blockIdx.x;
        if (bid >= 512) return;
        int idx = bid * 256 + tid;
        int sq = idx >> 6, d = idx & 63;
        float freq = expf(-(float)(d & ~1) * LOG1E4_64);
        float sn, cs;
        sincosf((float)sq * freq, &sn, &cs);
        ropec[idx] = cs; ropes[idx] = sn;
        return;
    }

    const void* W; u16* dst; int N;
    if (z == 0)      { W = Wq; dst = canon + C_WQ; N = 2048; }
    else if (z == 1) { W = Wk; dst = canon + C_WK; N = 512;  }
    else if (z == 2) { W = Wv; dst = canon + C_WV; N = 512;  }
    else             { W = Wo; dst = canon + C_WO; N = 2048; }
    const int n0 = blockIdx.x * 64, k0 = blockIdx.y * 64;
    if (n0 >= N) return;
    const int K = 2048;

    const bool is_f32 = detect_is_f32(hs_orig, tid, red, 4);

    #pragma unroll
    for (int it = 0; it < 4; ++it) {
        int e  = tid + it * 256;
        int kr = e >> 4, n4 = (e & 15) << 2;
        if (is_f32) {
            const float* s = (const float*)W + (size_t)(k0 + kr) * N + n0 + n4;
            float4 x = *(const float4*)s;
            Ts[n4+0][kr] = f2bf(x.x); Ts[n4+1][kr] = f2bf(x.y);
            Ts[n4+2][kr] = f2bf(x.z); Ts[n4+3][kr] = f2bf(x.w);
        } else {
            ushort4 u = *(const ushort4*)((const u16*)W + (size_t)(k0 + kr) * N + n0 + n4);
            Ts[n4+0][kr] = u.x; Ts[n4+1][kr] = u.y;
            Ts[n4+2][kr] = u.z; Ts[n4+3][kr] = u.w;
        }
    }
    __syncthreads();
    #pragma unroll
    for (int it = 0; it < 4; ++it) {
        int e  = tid + it * 256;
        int nr = e >> 4, k4 = (e & 15) << 2;
        ushort4 u;
        u.x = Ts[nr][k4+0]; u.y = Ts[nr][k4+1];
        u.z = Ts[nr][k4+2]; u.w = Ts[nr][k4+3];
        *(ushort4*)(dst + (size_t)(n0 + nr) * K + k0 + k4) = u;
    }
}

// ---------------------------------------------------------------------------
// Kernel 1: QKV projection (MFMA) + RoPE epilogue. 128x128 tile, BK=64,
// 512 threads = 8 waves (2x4), 64x32 per wave, demand<128 register contract.
// Reg-staged [128][72] pad + cross-barrier prefetch. XCD swizzle KEPT
// (R15 within-kernel A/B: 108 -> 97.6us, beyond noise — B-panel L2
// residency wins here despite 8x A re-fetch absorbed by L3).
// ---------------------------------------------------------------------------
__global__ __launch_bounds__(512, 4) __attribute__((amdgpu_waves_per_eu(4, 4)))
void gemm_qkv(const u16* __restrict__ hs, const u16* __restrict__ wqt,
              const u16* __restrict__ wkt, const u16* __restrict__ wvt,
              const float* __restrict__ ropec, const float* __restrict__ ropes,
              u16* __restrict__ qws, u16* __restrict__ kws, u16* __restrict__ vws)
{
    __shared__ __align__(16) u16 As[128][72];
    __shared__ __align__(16) u16 Bs[128][72];
    const int tid = threadIdx.x;
    const int w = tid >> 6, lane = tid & 63;
    const int l15 = lane & 15, quad = lane >> 4;
    const int wr = (w >> 2) * 64, wc = (w & 3) * 32;

    // XCD swizzle: nwg = 32*24 = 768, 96 per XCD (bijective: 768 % 8 == 0)
    const int bid = (int)(blockIdx.y * 32 + blockIdx.x);
    const int swz = (bid & 7) * 96 + (bid >> 3);
    const int row0 = (swz & 31) * 128;
    const int n0   = (swz >> 5) * 128;

    const u16* Wt; int nb, mode;
    if (n0 < 2048)      { Wt = wqt; nb = n0;        mode = 0; }
    else if (n0 < 2560) { Wt = wkt; nb = n0 - 2048; mode = 1; }
    else                { Wt = wvt; nb = n0 - 2560; mode = 2; }

    const int r0 = tid >> 3, c0 = (tid & 7) * 8;
    const u16* arow = hs + (size_t)(row0 + r0) * DMODEL + c0;
    const u16* brow = Wt + (size_t)(nb   + r0) * DMODEL + c0;

    f32x4 acc[4][2];
    #pragma unroll
    for (int mt = 0; mt < 4; ++mt)
        #pragma unroll
        for (int nt = 0; nt < 2; ++nt)
            acc[mt][nt] = (f32x4){0.f, 0.f, 0.f, 0.f};

    uint4 ra0, ra1, rb0, rb1;
#define LOADG(k0_) do {                                                       \
    ra0 = *(const uint4*)(arow + (k0_));                                      \
    ra1 = *(const uint4*)(arow + (size_t)64 * DMODEL + (k0_));                \
    rb0 = *(const uint4*)(brow + (k0_));                                      \
    rb1 = *(const uint4*)(brow + (size_t)64 * DMODEL + (k0_));                \
} while (0)
#define STORELDS() do {                                                       \
    *(uint4*)&As[r0][c0]      = ra0;                                          \
    *(uint4*)&As[r0 + 64][c0] = ra1;                                          \
    *(uint4*)&Bs[r0][c0]      = rb0;                                          \
    *(uint4*)&Bs[r0 + 64][c0] = rb1;                                          \
} while (0)

    LOADG(0);
    for (int k0 = 0; k0 < DMODEL; k0 += 64) {
        STORELDS();
        __syncthreads();
        if (k0 + 64 < DMODEL) LOADG(k0 + 64);
        #pragma unroll
        for (int ks = 0; ks < 2; ++ks) {
            v8bf a[4], b[2];
            #pragma unroll
            for (int mt = 0; mt < 4; ++mt)
                a[mt] = *(const v8bf*)&As[wr + 16*mt + l15][ks*32 + quad*8];
            #pragma unroll
            for (int nt = 0; nt < 2; ++nt)
                b[nt] = *(const v8bf*)&Bs[wc + 16*nt + l15][ks*32 + quad*8];
            #pragma unroll
            for (int mt = 0; mt < 4; ++mt)
                #pragma unroll
                for (int nt = 0; nt < 2; ++nt)
                    acc[mt][nt] = mfma16(a[mt], b[nt], acc[mt][nt]);
        }
        __syncthreads();
    }
#undef LOADG
#undef STORELDS

    #pragma unroll
    for (int mt = 0; mt < 4; ++mt) {
        #pragma unroll
        for (int nt = 0; nt < 2; ++nt) {
            int col  = n0 + wc + 16*nt + l15;
            int dcol = col & 63;
            #pragma unroll
            for (int reg = 0; reg < 4; ++reg) {
                int row = row0 + wr + 16*mt + quad*4 + reg;
                int b = row >> 11, s = row & (SEQ - 1);
                float val = acc[mt][nt][reg];
                if (mode < 2) {   // RoPE (pairs sit in adjacent lanes)
                    float c2 = ropec[(s << 6) + dcol];
                    float s2 = ropes[(s << 6) + dcol];
                    float partner = __shfl_xor(val, 1, 64);
                    val = (dcol & 1) ? (val * c2 + partner * s2)
                                     : (val * c2 - partner * s2);
                }
                if (mode == 0) {
                    int h = col >> 6;
                    qws[((size_t)((b*NH + h) * SEQ + s)) * DH + dcol] = f2bf_hw(val);
                } else if (mode == 1) {
                    int g = (col - 2048) >> 6;
                    kws[((size_t)((b*NG + g) * SEQ + s)) * DH + dcol] = f2bf_hw(val);
                } else {
                    int g = (col - 2560) >> 6;
                    vws[((size_t)((b*NG + g) * DH + dcol)) * SEQ + s] = f2bf_hw(val);
                }
            }
        }
    }
}

// ---------------------------------------------------------------------------
// Kernel 2: flash attention (R14-verified, unchanged). Two q-tiles per
// block; K/V staged once into LDS, 2-phase lockstep with next-tile prefetch;
// swapped QK^T (mfma(K,Q)); packed P-store; causal mask s_local > 16w+l15;
// l via ones-fragment MFMA appended to PV.
// ---------------------------------------------------------------------------
__global__ __launch_bounds__(256, 4)
void attn(const u16* __restrict__ qws, const u16* __restrict__ kws,
          const u16* __restrict__ vws, u16* __restrict__ ctx)
{
    __shared__ __align__(16) u16 Ks[64][72];      // K tile [s_local][d]
    __shared__ __align__(16) u16 Vs[64][72];      // V tile [d][s_local]
    __shared__ __align__(16) u16 Ps[4][16][72];   // wave-private P [q][s]
    const int tid = threadIdx.x;
    const int w = tid >> 6, lane = tid & 63;
    const int l15 = lane & 15, quad = lane >> 4;
    const int sr = tid >> 3;          // staging row 0..31 (+32 second pass)
    const int sc = (tid & 7) * 8;     // staging col (u16 units, 16B chunks)

    const int h = blockIdx.y, b = blockIdx.z;
    const int g = h >> 2;

    const float slope = exp2f(-0.25f * (float)(h + 1));
    const u16* kbase  = kws + (size_t)(b*NG + g) * SEQ * DH;
    const u16* vtbase = vws + (size_t)(b*NG + g) * DH * SEQ;   // [d][s]
    const u16* qhead  = qws + (size_t)(b*NH + h) * SEQ * DH;

    const float Ac = 0.125f * (LOG2E / 15.0f);
    const float Bc = -slope * 0.125f * (LOG2E / 15.0f);
    const float C3 = -60.0f * LOG2E;
    // swapped bias: q_local = 16w + l15, s_local = 16mt + 4quad + rg
    float bdw[4][4];
    #pragma unroll
    for (int mt = 0; mt < 4; ++mt)
        #pragma unroll
        for (int reg = 0; reg < 4; ++reg)
            bdw[mt][reg] = Bc * (float)((16*w + l15) - (16*mt + 4*quad + reg));

    // all-ones B fragment for the l-row MFMA
    v8bf vones;
    #pragma unroll
    for (int j = 0; j < 8; ++j) vones[j] = (__bf16)1.0f;

    uint4 rk0, rk1, rv0, rv1;   // in-flight staging registers (one K/V tile)

#define LOADG(kt_) do {                                                       \
    const u16* kp_ = kbase + (size_t)(kt_) * (64 * DH);                       \
    rk0 = *(const uint4*)(kp_ + sr * DH + sc);                                \
    rk1 = *(const uint4*)(kp_ + (sr + 32) * DH + sc);                         \
    const u16* vp_ = vtbase + (size_t)(kt_) * 64;                             \
    rv0 = *(const uint4*)(vp_ + (size_t)sr * SEQ + sc);                       \
    rv1 = *(const uint4*)(vp_ + (size_t)(sr + 32) * SEQ + sc);                \
} while (0)

#define STORELDS() do {                                                       \
    *(uint4*)&Ks[sr][sc]      = rk0;                                          \
    *(uint4*)&Ks[sr + 32][sc] = rk1;                                          \
    *(uint4*)&Vs[sr][sc]      = rv0;                                          \
    *(uint4*)&Vs[sr + 32][sc] = rv1;                                          \
} while (0)

#define COMPUTE(kt_, DIAGC) do {                                              \
    f32x4 sacc_[4];                                                           \
    _Pragma("unroll")                                                         \
    for (int mt_ = 0; mt_ < 4; ++mt_) sacc_[mt_] = (f32x4){0.f,0.f,0.f,0.f};  \
    _Pragma("unroll")                                                         \
    for (int ks_ = 0; ks_ < 2; ++ks_)                                         \
        _Pragma("unroll")                                                     \
        for (int mt_ = 0; mt_ < 4; ++mt_) {                                   \
            v8bf kf_ = *(const v8bf*)&Ks[16*mt_ + l15][ks_*32 + quad*8];      \
            sacc_[mt_] = mfma16(kf_, qa[ks_], sacc_[mt_]);                    \
        }                                                                     \
    const float tb_ = Bc * (float)(q0 - (kt_) * 64);                          \
    _Pragma("unroll")                                                         \
    for (int mt_ = 0; mt_ < 4; ++mt_) {                                       \
        float pv_[4];                                                         \
        _Pragma("unroll")                                                     \
        for (int rg_ = 0; rg_ < 4; ++rg_) {                                   \
            float arg_ = fmaf(sacc_[mt_][rg_], Ac, bdw[mt_][rg_] + tb_);      \
            float wv_  = __builtin_amdgcn_exp2f(arg_);                        \
            float rr_  = __builtin_amdgcn_rcpf(wv_ + 1.0f);                   \
            float p_   = __builtin_amdgcn_exp2f(rr_ * C3);                    \
            if (DIAGC && (16*mt_ + 4*quad + rg_) > (16*w + l15)) p_ = 0.0f;   \
            pv_[rg_] = p_;                                                    \
        }                                                                     \
        uint2 pk_;                                                            \
        pk_.x = f2bf_pk(pv_[0], pv_[1]);                                      \
        pk_.y = f2bf_pk(pv_[2], pv_[3]);                                      \
        *(uint2*)&Ps[w][l15][16*mt_ + quad*4] = pk_;                          \
    }                                                                         \
    _Pragma("unroll")                                                         \
    for (int ks_ = 0; ks_ < 2; ++ks_) {                                       \
        v8bf pa_ = *(const v8bf*)&Ps[w][l15][ks_*32 + quad*8];                \
        _Pragma("unroll")                                                     \
        for (int dt_ = 0; dt_ < 4; ++dt_) {                                   \
            v8bf vf_ = *(const v8bf*)&Vs[16*dt_ + l15][ks_*32 + quad*8];      \
            o[dt_] = mfma16(pa_, vf_, o[dt_]);                                \
        }                                                                     \
        lacc = mfma16(pa_, vones, lacc);                                      \
    }                                                                         \
} while (0)

    #pragma unroll 1
    for (int half = 0; half < 2; ++half) {
        const int qt = half ? 31 - (int)blockIdx.x : (int)blockIdx.x;
        const int q0 = qt * 64;

        // Q frags in registers: rows q0+16w+l15 (valid as A or B operand)
        const u16* qrow = qhead + (size_t)(q0 + 16*w + l15) * DH;
        v8bf qa[2];
        qa[0] = *(const v8bf*)(qrow + 0*32 + quad*8);
        qa[1] = *(const v8bf*)(qrow + 1*32 + quad*8);

        f32x4 o[4];
        #pragma unroll
        for (int dt = 0; dt < 4; ++dt) o[dt] = (f32x4){0.f, 0.f, 0.f, 0.f};
        f32x4 lacc = (f32x4){0.f, 0.f, 0.f, 0.f};   // l[q=quad*4+reg], any col

        LOADG(0);
        for (int kt = 0; kt < qt; ++kt) {
            STORELDS();
            __syncthreads();
            LOADG(kt + 1);          // prefetch next tile while computing this one
            COMPUTE(kt, 0);
            __syncthreads();
        }
        STORELDS();                 // diag tile
        __syncthreads();
        COMPUTE(qt, 1);
        __syncthreads();

        // epilogue: l already in lacc[reg] (ones-MFMA) — no shuffles needed
        #pragma unroll
        for (int reg = 0; reg < 4; ++reg) {
            float linv = __builtin_amdgcn_rcpf(lacc[reg]);
            int s = q0 + 16*w + quad*4 + reg;
            u16* crow = ctx + (size_t)(b*SEQ + s) * DMODEL + h*64 + l15;
            #pragma unroll
            for (int dt = 0; dt < 4; ++dt)
                crow[16*dt] = f2bf_hw(o[dt][reg] * linv);
        }
    }
#undef LOADG
#undef STORELDS
#undef COMPUTE
}

// ---------------------------------------------------------------------------
// Kernel 3: out = ctx @ Wo + bo. Reg-staged 512-thread structure (R14
// config). XCD swizzle REVERTED here (R15: total regressed 327->342 with
// both swizzles; oproj's lower compute-per-byte can't hide the 8x ctx
// re-fetch the swizzle induces). LAUNCH WITH 512 THREADS.
// ---------------------------------------------------------------------------
__global__ __launch_bounds__(512, 4) __attribute__((amdgpu_waves_per_eu(4, 4)))
void oproj(const u16* __restrict__ ctx, const u16* __restrict__ wot,
           const u16* __restrict__ bo, const u16* __restrict__ hs_orig,
           void* __restrict__ outp)
{
    __shared__ float red[8];
    __shared__ __align__(16) u16 As[128][72];
    __shared__ __align__(16) u16 Bs[128][72];
    const int tid = threadIdx.x;
    const bool is_f32 = detect_is_f32(hs_orig, tid, red, 8);
    const int w = tid >> 6, lane = tid & 63;
    const int l15 = lane & 15, quad = lane >> 4;
    const int wr = (w >> 2) * 64, wc = (w & 3) * 32;
    const int row0 = blockIdx.x * 128;
    const int n0   = blockIdx.y * 128;

    const int r0 = tid >> 3, c0 = (tid & 7) * 8;
    const u16* arow = ctx + (size_t)(row0 + r0) * DMODEL + c0;
    const u16* brow = wot + (size_t)(n0   + r0) * DMODEL + c0;

    f32x4 acc[4][2];
    #pragma unroll
    for (int mt = 0; mt < 4; ++mt)
        #pragma unroll
        for (int nt = 0; nt < 2; ++nt)
            acc[mt][nt] = (f32x4){0.f, 0.f, 0.f, 0.f};

    uint4 ra0, ra1, rb0, rb1;
#define LOADG(k0_) do {                                                       \
    ra0 = *(const uint4*)(arow + (k0_));                                      \
    ra1 = *(const uint4*)(arow + (size_t)64 * DMODEL + (k0_));                \
    rb0 = *(const uint4*)(brow + (k0_));                                      \
    rb1 = *(const uint4*)(brow + (size_t)64 * DMODEL + (k0_));                \
} while (0)
#define STORELDS() do {                                                       \
    *(uint4*)&As[r0][c0]      = ra0;                                          \
    *(uint4*)&As[r0 + 64][c0] = ra1;                                          \
    *(uint4*)&Bs[r0][c0]      = rb0;                                          \
    *(uint4*)&Bs[r0 + 64][c0] = rb1;                                          \
} while (0)

    LOADG(0);
    for (int k0 = 0; k0 < DMODEL; k0 += 64) {
        STORELDS();
        __syncthreads();
        if (k0 + 64 < DMODEL) LOADG(k0 + 64);
        #pragma unroll
        for (int ks = 0; ks < 2; ++ks) {
            v8bf a[4], b[2];
            #pragma unroll
            for (int mt = 0; mt < 4; ++mt)
                a[mt] = *(const v8bf*)&As[wr + 16*mt + l15][ks*32 + quad*8];
            #pragma unroll
            for (int nt = 0; nt < 2; ++nt)
                b[nt] = *(const v8bf*)&Bs[wc + 16*nt + l15][ks*32 + quad*8];
            #pragma unroll
            for (int mt = 0; mt < 4; ++mt)
                #pragma unroll
                for (int nt = 0; nt < 2; ++nt)
                    acc[mt][nt] = mfma16(a[mt], b[nt], acc[mt][nt]);
        }
        __syncthreads();
    }
#undef LOADG
#undef STORELDS

    #pragma unroll
    for (int mt = 0; mt < 4; ++mt) {
        #pragma unroll
        for (int nt = 0; nt < 2; ++nt) {
            int col = n0 + wc + 16*nt + l15;
            float bias = bf2f(bo[col]);
            #pragma unroll
            for (int reg = 0; reg < 4; ++reg) {
                int row = row0 + wr + 16*mt + quad*4 + reg;
                float val = acc[mt][nt][reg] + bias;
                if (is_f32) ((float*)outp)[(size_t)row * DMODEL + col] = val;
                else        ((u16*)outp)[(size_t)row * DMODEL + col]   = f2bf(val);
            }
        }
    }
}

extern "C" void kernel_launch(void* const* d_in, const int* in_sizes, int n_in,
                              void* d_out, int out_size, void* d_ws, size_t ws_size,
                              hipStream_t stream) {
    u16* ws = (u16*)d_ws;
    u16* canon = ws;
    u16* qws = ws + W_Q;
    u16* kws = ws + W_K;
    u16* vws = ws + W_V;
    u16* ctxp = ws + W_CTX;
    float* ropec = (float*)(ws + W_CTX);          // transient (dead before attn writes ctx)
    float* ropes = ropec + SEQ * DH;
    const u16* hs_raw = (const u16*)d_in[0];

    conv_hs_bo<<<dim3(4097), 256, 0, stream>>>(d_in[0], d_in[5], canon);
    transp_all<<<dim3(32, 32, 5), 256, 0, stream>>>(d_in[1], d_in[2], d_in[3],
        d_in[4], canon, hs_raw, ropec, ropes);
    gemm_qkv<<<dim3(32, 24), 512, 0, stream>>>(canon + C_HS, canon + C_WQ,
        canon + C_WK, canon + C_WV, ropec, ropes, qws, kws, vws);
    attn<<<dim3(16, NH, 2), 256, 0, stream>>>(qws, kws, vws, ctxp);
    oproj<<<dim3(32, 16), 512, 0, stream>>>(ctxp, canon + C_WO, canon + C_BO, hs_raw, d_out);
}

// Round 17
// 327.867 us; speedup vs baseline: 1.0430x; 1.0315x over previous
//
#include <hip/hip_runtime.h>
#include <hip/hip_bf16.h>
#include <math.h>

#define DMODEL 2048
#define SEQ    2048
#define NH     32
#define NG     8
#define DH     64

typedef unsigned short u16;
typedef unsigned int u32;
using v8bf  = __attribute__((ext_vector_type(8))) __bf16;
using f32x4 = __attribute__((ext_vector_type(4))) float;

__device__ __forceinline__ float bf2f(u16 u) {
    unsigned int x = ((unsigned int)u) << 16;
    return __uint_as_float(x);
}
__device__ __forceinline__ u16 f2bf(float f) {
    unsigned int x = __float_as_uint(f);
    unsigned int r = (x + 0x7fffu + ((x >> 16) & 1u)) >> 16;
    return (u16)r;
}
// HW RNE convert (single v_cvt vs 4 int ops) — bit-identical to f2bf for normals.
__device__ __forceinline__ u16 f2bf_hw(float f) {
    __bf16 b = (__bf16)f;
    return __builtin_bit_cast(u16, b);
}
// Pack two floats to bf16x2 in a u32 (2 v_cvt + 1 v_lshl_or).
__device__ __forceinline__ u32 f2bf_pk(float lo, float hi) {
    return (u32)f2bf_hw(lo) | ((u32)f2bf_hw(hi) << 16);
}
__device__ __forceinline__ f32x4 mfma16(v8bf a, v8bf b, f32x4 c) {
    return __builtin_amdgcn_mfma_f32_16x16x32_bf16(a, b, c, 0, 0, 0);
}

#define LOG1E4_64 0.14391156509880297f
#define LOG2E     1.4426950408889634f

// ws layout (u16 element offsets). Weights TRANSPOSED [n][k].
#define C_HS   0u
#define C_WQ   8388608u
#define C_WK   12582912u
#define C_WV   13631488u
#define C_WO   14680064u
#define C_BO   18874368u
#define W_Q    18876416u   // [b,h][s][d]
#define W_K    27265024u   // [b,g][s][d]
#define W_V    29362176u   // [b,g][d][s]
#define W_CTX  31459328u   // transient RoPE table -> bf16 ctx

// ---------------------------------------------------------------------------
// Runtime input-dtype detection. nw = number of waves in the block.
// ---------------------------------------------------------------------------
__device__ __forceinline__ bool detect_is_f32(const u16* hsu, int tid, float* red, int nw)
{
    ushort4 a = *(const ushort4*)(hsu + tid * 8);
    ushort4 b = *(const ushort4*)(hsu + tid * 8 + 4);
    u16 vals[8] = {a.x, a.y, a.z, a.w, b.x, b.y, b.z, b.w};
    float mymax = 0.0f;
    #pragma unroll
    for (int e = 0; e < 8; ++e) {
        float av = fabsf(bf2f(vals[e]));
        if (!(av < 1.0e30f)) av = 1.0e30f;
        mymax = fmaxf(mymax, av);
    }
    #pragma unroll
    for (int off = 1; off < 64; off <<= 1)
        mymax = fmaxf(mymax, __shfl_xor(mymax, off, 64));
    if ((tid & 63) == 0) red[tid >> 6] = mymax;
    __syncthreads();
    float m = red[0];
    for (int i = 1; i < nw; ++i) m = fmaxf(m, red[i]);
    __syncthreads();
    return m > 1.0e6f;
}

// ---------------------------------------------------------------------------
// Prelude A: convert hs + bo to canonical bf16.
// ---------------------------------------------------------------------------
__global__ __launch_bounds__(256)
void conv_hs_bo(const void* __restrict__ hs, const void* __restrict__ bo,
                u16* __restrict__ canon)
{
    __shared__ float red[4];
    const int tid = threadIdx.x;
    const bool is_f32 = detect_is_f32((const u16*)hs, tid, red, 4);
    unsigned int g = (blockIdx.x * 256u + tid) * 8u;
    const void* src; unsigned int loc; u16* dst;
    if (g < 8388608u) { src = hs; loc = g;            dst = canon + C_HS + g; }
    else              { src = bo; loc = g - 8388608u; dst = canon + C_BO + loc; }

    ushort4 o0, o1;
    if (is_f32) {
        const float* f = (const float*)src + loc;
        float4 x = *(const float4*)f;
        float4 y = *(const float4*)(f + 4);
        o0.x = f2bf(x.x); o0.y = f2bf(x.y); o0.z = f2bf(x.z); o0.w = f2bf(x.w);
        o1.x = f2bf(y.x); o1.y = f2bf(y.y); o1.z = f2bf(y.z); o1.w = f2bf(y.w);
    } else {
        const u16* u = (const u16*)src + loc;
        o0 = *(const ushort4*)u;
        o1 = *(const ushort4*)(u + 4);
    }
    *(ushort4*)dst       = o0;
    *(ushort4*)(dst + 4) = o1;
}

// ---------------------------------------------------------------------------
// Prelude B (merged): all four weight transposes + RoPE table in ONE launch.
// blockIdx.z: 0=Wq 1=Wk 2=Wv 3=Wo (transpose-convert, K=2048), 4=rope table.
// Uniform per-block early exits (before any __syncthreads).
// ---------------------------------------------------------------------------
__global__ __launch_bounds__(256)
void transp_all(const void* __restrict__ Wq, const void* __restrict__ Wk,
                const void* __restrict__ Wv, const void* __restrict__ Wo,
                u16* __restrict__ canon, const u16* __restrict__ hs_orig,
                float* __restrict__ ropec, float* __restrict__ ropes)
{
    __shared__ float red[4];
    __shared__ u16 Ts[64][68];
    const int tid = threadIdx.x;
    const int z = blockIdx.z;

    if (z == 4) {   // RoPE table: 512 blocks worth of work
        int bid = blockIdx.y * 32 + blockIdx.x;
        if (bid >= 512) return;
        int idx = bid * 256 + tid;
        int sq = idx >> 6, d = idx & 63;
        float freq = expf(-(float)(d & ~1) * LOG1E4_64);
        float sn, cs;
        sincosf((float)sq * freq, &sn, &cs);
        ropec[idx] = cs; ropes[idx] = sn;
        return;
    }

    const void* W; u16* dst; int N;
    if (z == 0)      { W = Wq; dst = canon + C_WQ; N = 2048; }
    else if (z == 1) { W = Wk; dst = canon + C_WK; N = 512;  }
    else if (z == 2) { W = Wv; dst = canon + C_WV; N = 512;  }
    else             { W = Wo; dst = canon + C_WO; N = 2048; }
    const int n0 = blockIdx.x * 64, k0 = blockIdx.y * 64;
    if (n0 >= N) return;
    const int K = 2048;

    const bool is_f32 = detect_is_f32(hs_orig, tid, red, 4);

    #pragma unroll
    for (int it = 0; it < 4; ++it) {
        int e  = tid + it * 256;
        int kr = e >> 4, n4 = (e & 15) << 2;
        if (is_f32) {
            const float* s = (const float*)W + (size_t)(k0 + kr) * N + n0 + n4;
            float4 x = *(const float4*)s;
            Ts[n4+0][kr] = f2bf(x.x); Ts[n4+1][kr] = f2bf(x.y);
            Ts[n4+2][kr] = f2bf(x.z); Ts[n4+3][kr] = f2bf(x.w);
        } else {
            ushort4 u = *(const ushort4*)((const u16*)W + (size_t)(k0 + kr) * N + n0 + n4);
            Ts[n4+0][kr] = u.x; Ts[n4+1][kr] = u.y;
            Ts[n4+2][kr] = u.z; Ts[n4+3][kr] = u.w;
        }
    }
    __syncthreads();
    #pragma unroll
    for (int it = 0; it < 4; ++it) {
        int e  = tid + it * 256;
        int nr = e >> 4, k4 = (e & 15) << 2;
        ushort4 u;
        u.x = Ts[nr][k4+0]; u.y = Ts[nr][k4+1];
        u.z = Ts[nr][k4+2]; u.w = Ts[nr][k4+3];
        *(ushort4*)(dst + (size_t)(n0 + nr) * K + k0 + k4) = u;
    }
}

// ---------------------------------------------------------------------------
// Kernel 1: QKV projection (MFMA) + RoPE epilogue. 128x128 tile, BK=64,
// 512 threads = 8 waves (2x4), 64x32 per wave, demand<128 register contract
// (R4/R5/R12: acc[4][4]@256thr spills regardless of launch-bounds hints).
// Reg-staged [128][72] pad + cross-barrier prefetch (R10: gload_lds worse).
// NO XCD swizzle: R15/R16 full-pipeline A/B showed the swizzle speeds this
// kernel (108->99us) but regresses TOTAL (327 -> 342/338) via 8x A re-fetch
// L3 pressure on downstream kernels. R14 config = best measured total.
// ---------------------------------------------------------------------------
__global__ __launch_bounds__(512, 4) __attribute__((amdgpu_waves_per_eu(4, 4)))
void gemm_qkv(const u16* __restrict__ hs, const u16* __restrict__ wqt,
              const u16* __restrict__ wkt, const u16* __restrict__ wvt,
              const float* __restrict__ ropec, const float* __restrict__ ropes,
              u16* __restrict__ qws, u16* __restrict__ kws, u16* __restrict__ vws)
{
    __shared__ __align__(16) u16 As[128][72];
    __shared__ __align__(16) u16 Bs[128][72];
    const int tid = threadIdx.x;
    const int w = tid >> 6, lane = tid & 63;
    const int l15 = lane & 15, quad = lane >> 4;
    const int wr = (w >> 2) * 64, wc = (w & 3) * 32;
    const int row0 = blockIdx.x * 128;
    const int n0   = blockIdx.y * 128;

    const u16* Wt; int nb, mode;
    if (n0 < 2048)      { Wt = wqt; nb = n0;        mode = 0; }
    else if (n0 < 2560) { Wt = wkt; nb = n0 - 2048; mode = 1; }
    else                { Wt = wvt; nb = n0 - 2560; mode = 2; }

    const int r0 = tid >> 3, c0 = (tid & 7) * 8;
    const u16* arow = hs + (size_t)(row0 + r0) * DMODEL + c0;
    const u16* brow = Wt + (size_t)(nb   + r0) * DMODEL + c0;

    f32x4 acc[4][2];
    #pragma unroll
    for (int mt = 0; mt < 4; ++mt)
        #pragma unroll
        for (int nt = 0; nt < 2; ++nt)
            acc[mt][nt] = (f32x4){0.f, 0.f, 0.f, 0.f};

    uint4 ra0, ra1, rb0, rb1;
#define LOADG(k0_) do {                                                       \
    ra0 = *(const uint4*)(arow + (k0_));                                      \
    ra1 = *(const uint4*)(arow + (size_t)64 * DMODEL + (k0_));                \
    rb0 = *(const uint4*)(brow + (k0_));                                      \
    rb1 = *(const uint4*)(brow + (size_t)64 * DMODEL + (k0_));                \
} while (0)
#define STORELDS() do {                                                       \
    *(uint4*)&As[r0][c0]      = ra0;                                          \
    *(uint4*)&As[r0 + 64][c0] = ra1;                                          \
    *(uint4*)&Bs[r0][c0]      = rb0;                                          \
    *(uint4*)&Bs[r0 + 64][c0] = rb1;                                          \
} while (0)

    LOADG(0);
    for (int k0 = 0; k0 < DMODEL; k0 += 64) {
        STORELDS();
        __syncthreads();
        if (k0 + 64 < DMODEL) LOADG(k0 + 64);
        #pragma unroll
        for (int ks = 0; ks < 2; ++ks) {
            v8bf a[4], b[2];
            #pragma unroll
            for (int mt = 0; mt < 4; ++mt)
                a[mt] = *(const v8bf*)&As[wr + 16*mt + l15][ks*32 + quad*8];
            #pragma unroll
            for (int nt = 0; nt < 2; ++nt)
                b[nt] = *(const v8bf*)&Bs[wc + 16*nt + l15][ks*32 + quad*8];
            #pragma unroll
            for (int mt = 0; mt < 4; ++mt)
                #pragma unroll
                for (int nt = 0; nt < 2; ++nt)
                    acc[mt][nt] = mfma16(a[mt], b[nt], acc[mt][nt]);
        }
        __syncthreads();
    }
#undef LOADG
#undef STORELDS

    #pragma unroll
    for (int mt = 0; mt < 4; ++mt) {
        #pragma unroll
        for (int nt = 0; nt < 2; ++nt) {
            int col  = n0 + wc + 16*nt + l15;
            int dcol = col & 63;
            #pragma unroll
            for (int reg = 0; reg < 4; ++reg) {
                int row = row0 + wr + 16*mt + quad*4 + reg;
                int b = row >> 11, s = row & (SEQ - 1);
                float val = acc[mt][nt][reg];
                if (mode < 2) {   // RoPE (pairs sit in adjacent lanes)
                    float c2 = ropec[(s << 6) + dcol];
                    float s2 = ropes[(s << 6) + dcol];
                    float partner = __shfl_xor(val, 1, 64);
                    val = (dcol & 1) ? (val * c2 + partner * s2)
                                     : (val * c2 - partner * s2);
                }
                if (mode == 0) {
                    int h = col >> 6;
                    qws[((size_t)((b*NH + h) * SEQ + s)) * DH + dcol] = f2bf_hw(val);
                } else if (mode == 1) {
                    int g = (col - 2048) >> 6;
                    kws[((size_t)((b*NG + g) * SEQ + s)) * DH + dcol] = f2bf_hw(val);
                } else {
                    int g = (col - 2560) >> 6;
                    vws[((size_t)((b*NG + g) * DH + dcol)) * SEQ + s] = f2bf_hw(val);
                }
            }
        }
    }
}

// ---------------------------------------------------------------------------
// Kernel 2: flash attention (R14-verified). Two q-tiles per block; K/V
// staged once into LDS, 2-phase lockstep with next-tile prefetch; swapped
// QK^T (mfma(K,Q)); packed P-store; causal mask s_local > 16w+l15; l via
// ones-fragment MFMA appended to PV.
// ---------------------------------------------------------------------------
__global__ __launch_bounds__(256, 4)
void attn(const u16* __restrict__ qws, const u16* __restrict__ kws,
          const u16* __restrict__ vws, u16* __restrict__ ctx)
{
    __shared__ __align__(16) u16 Ks[64][72];      // K tile [s_local][d]
    __shared__ __align__(16) u16 Vs[64][72];      // V tile [d][s_local]
    __shared__ __align__(16) u16 Ps[4][16][72];   // wave-private P [q][s]
    const int tid = threadIdx.x;
    const int w = tid >> 6, lane = tid & 63;
    const int l15 = lane & 15, quad = lane >> 4;
    const int sr = tid >> 3;          // staging row 0..31 (+32 second pass)
    const int sc = (tid & 7) * 8;     // staging col (u16 units, 16B chunks)

    const int h = blockIdx.y, b = blockIdx.z;
    const int g = h >> 2;

    const float slope = exp2f(-0.25f * (float)(h + 1));
    const u16* kbase  = kws + (size_t)(b*NG + g) * SEQ * DH;
    const u16* vtbase = vws + (size_t)(b*NG + g) * DH * SEQ;   // [d][s]
    const u16* qhead  = qws + (size_t)(b*NH + h) * SEQ * DH;

    const float Ac = 0.125f * (LOG2E / 15.0f);
    const float Bc = -slope * 0.125f * (LOG2E / 15.0f);
    const float C3 = -60.0f * LOG2E;
    // swapped bias: q_local = 16w + l15, s_local = 16mt + 4quad + rg
    float bdw[4][4];
    #pragma unroll
    for (int mt = 0; mt < 4; ++mt)
        #pragma unroll
        for (int reg = 0; reg < 4; ++reg)
            bdw[mt][reg] = Bc * (float)((16*w + l15) - (16*mt + 4*quad + reg));

    // all-ones B fragment for the l-row MFMA
    v8bf vones;
    #pragma unroll
    for (int j = 0; j < 8; ++j) vones[j] = (__bf16)1.0f;

    uint4 rk0, rk1, rv0, rv1;   // in-flight staging registers (one K/V tile)

#define LOADG(kt_) do {                                                       \
    const u16* kp_ = kbase + (size_t)(kt_) * (64 * DH);                       \
    rk0 = *(const uint4*)(kp_ + sr * DH + sc);                                \
    rk1 = *(const uint4*)(kp_ + (sr + 32) * DH + sc);                         \
    const u16* vp_ = vtbase + (size_t)(kt_) * 64;                             \
    rv0 = *(const uint4*)(vp_ + (size_t)sr * SEQ + sc);                       \
    rv1 = *(const uint4*)(vp_ + (size_t)(sr + 32) * SEQ + sc);                \
} while (0)

#define STORELDS() do {                                                       \
    *(uint4*)&Ks[sr][sc]      = rk0;                                          \
    *(uint4*)&Ks[sr + 32][sc] = rk1;                                          \
    *(uint4*)&Vs[sr][sc]      = rv0;                                          \
    *(uint4*)&Vs[sr + 32][sc] = rv1;                                          \
} while (0)

#define COMPUTE(kt_, DIAGC) do {                                              \
    f32x4 sacc_[4];                                                           \
    _Pragma("unroll")                                                         \
    for (int mt_ = 0; mt_ < 4; ++mt_) sacc_[mt_] = (f32x4){0.f,0.f,0.f,0.f};  \
    _Pragma("unroll")                                                         \
    for (int ks_ = 0; ks_ < 2; ++ks_)                                         \
        _Pragma("unroll")                                                     \
        for (int mt_ = 0; mt_ < 4; ++mt_) {                                   \
            v8bf kf_ = *(const v8bf*)&Ks[16*mt_ + l15][ks_*32 + quad*8];      \
            sacc_[mt_] = mfma16(kf_, qa[ks_], sacc_[mt_]);                    \
        }                                                                     \
    const float tb_ = Bc * (float)(q0 - (kt_) * 64);                          \
    _Pragma("unroll")                                                         \
    for (int mt_ = 0; mt_ < 4; ++mt_) {                                       \
        float pv_[4];                                                         \
        _Pragma("unroll")                                                     \
        for (int rg_ = 0; rg_ < 4; ++rg_) {                                   \
            float arg_ = fmaf(sacc_[mt_][rg_], Ac, bdw[mt_][rg_] + tb_);      \
            float wv_  = __builtin_amdgcn_exp2f(arg_);                        \
            float rr_  = __builtin_amdgcn_rcpf(wv_ + 1.0f);                   \
            float p_   = __builtin_amdgcn_exp2f(rr_ * C3);                    \
            if (DIAGC && (16*mt_ + 4*quad + rg_) > (16*w + l15)) p_ = 0.0f;   \
            pv_[rg_] = p_;                                                    \
        }                                                                     \
        uint2 pk_;                                                            \
        pk_.x = f2bf_pk(pv_[0], pv_[1]);                                      \
        pk_.y = f2bf_pk(pv_[2], pv_[3]);                                      \
        *(uint2*)&Ps[w][l15][16*mt_ + quad*4] = pk_;                          \
    }                                                                         \
    _Pragma("unroll")                                                         \
    for (int ks_ = 0; ks_ < 2; ++ks_) {                                       \
        v8bf pa_ = *(const v8bf*)&Ps[w][l15][ks_*32 + quad*8];                \
        _Pragma("unroll")                                                     \
        for (int dt_ = 0; dt_ < 4; ++dt_) {                                   \
            v8bf vf_ = *(const v8bf*)&Vs[16*dt_ + l15][ks_*32 + quad*8];      \
            o[dt_] = mfma16(pa_, vf_, o[dt_]);                                \
        }                                                                     \
        lacc = mfma16(pa_, vones, lacc);                                      \
    }                                                                         \
} while (0)

    #pragma unroll 1
    for (int half = 0; half < 2; ++half) {
        const int qt = half ? 31 - (int)blockIdx.x : (int)blockIdx.x;
        const int q0 = qt * 64;

        // Q frags in registers: rows q0+16w+l15 (valid as A or B operand)
        const u16* qrow = qhead + (size_t)(q0 + 16*w + l15) * DH;
        v8bf qa[2];
        qa[0] = *(const v8bf*)(qrow + 0*32 + quad*8);
        qa[1] = *(const v8bf*)(qrow + 1*32 + quad*8);

        f32x4 o[4];
        #pragma unroll
        for (int dt = 0; dt < 4; ++dt) o[dt] = (f32x4){0.f, 0.f, 0.f, 0.f};
        f32x4 lacc = (f32x4){0.f, 0.f, 0.f, 0.f};   // l[q=quad*4+reg], any col

        LOADG(0);
        for (int kt = 0; kt < qt; ++kt) {
            STORELDS();
            __syncthreads();
            LOADG(kt + 1);          // prefetch next tile while computing this one
            COMPUTE(kt, 0);
            __syncthreads();
        }
        STORELDS();                 // diag tile
        __syncthreads();
        COMPUTE(qt, 1);
        __syncthreads();

        // epilogue: l already in lacc[reg] (ones-MFMA) — no shuffles needed
        #pragma unroll
        for (int reg = 0; reg < 4; ++reg) {
            float linv = __builtin_amdgcn_rcpf(lacc[reg]);
            int s = q0 + 16*w + quad*4 + reg;
            u16* crow = ctx + (size_t)(b*SEQ + s) * DMODEL + h*64 + l15;
            #pragma unroll
            for (int dt = 0; dt < 4; ++dt)
                crow[16*dt] = f2bf_hw(o[dt][reg] * linv);
        }
    }
#undef LOADG
#undef STORELDS
#undef COMPUTE
}

// ---------------------------------------------------------------------------
// Kernel 3: out = ctx @ Wo + bo. Reg-staged 512-thread structure (R14
// config, no swizzle). LAUNCH WITH 512 THREADS.
// ---------------------------------------------------------------------------
__global__ __launch_bounds__(512, 4) __attribute__((amdgpu_waves_per_eu(4, 4)))
void oproj(const u16* __restrict__ ctx, const u16* __restrict__ wot,
           const u16* __restrict__ bo, const u16* __restrict__ hs_orig,
           void* __restrict__ outp)
{
    __shared__ float red[8];
    __shared__ __align__(16) u16 As[128][72];
    __shared__ __align__(16) u16 Bs[128][72];
    const int tid = threadIdx.x;
    const bool is_f32 = detect_is_f32(hs_orig, tid, red, 8);
    const int w = tid >> 6, lane = tid & 63;
    const int l15 = lane & 15, quad = lane >> 4;
    const int wr = (w >> 2) * 64, wc = (w & 3) * 32;
    const int row0 = blockIdx.x * 128;
    const int n0   = blockIdx.y * 128;

    const int r0 = tid >> 3, c0 = (tid & 7) * 8;
    const u16* arow = ctx + (size_t)(row0 + r0) * DMODEL + c0;
    const u16* brow = wot + (size_t)(n0   + r0) * DMODEL + c0;

    f32x4 acc[4][2];
    #pragma unroll
    for (int mt = 0; mt < 4; ++mt)
        #pragma unroll
        for (int nt = 0; nt < 2; ++nt)
            acc[mt][nt] = (f32x4){0.f, 0.f, 0.f, 0.f};

    uint4 ra0, ra1, rb0, rb1;
#define LOADG(k0_) do {                                                       \
    ra0 = *(const uint4*)(arow + (k0_));                                      \
    ra1 = *(const uint4*)(arow + (size_t)64 * DMODEL + (k0_));                \
    rb0 = *(const uint4*)(brow + (k0_));                                      \
    rb1 = *(const uint4*)(brow + (size_t)64 * DMODEL + (k0_));                \
} while (0)
#define STORELDS() do {                                                       \
    *(uint4*)&As[r0][c0]      = ra0;                                          \
    *(uint4*)&As[r0 + 64][c0] = ra1;                                          \
    *(uint4*)&Bs[r0][c0]      = rb0;                                          \
    *(uint4*)&Bs[r0 + 64][c0] = rb1;                                          \
} while (0)

    LOADG(0);
    for (int k0 = 0; k0 < DMODEL; k0 += 64) {
        STORELDS();
        __syncthreads();
        if (k0 + 64 < DMODEL) LOADG(k0 + 64);
        #pragma unroll
        for (int ks = 0; ks < 2; ++ks) {
            v8bf a[4], b[2];
            #pragma unroll
            for (int mt = 0; mt < 4; ++mt)
                a[mt] = *(const v8bf*)&As[wr + 16*mt + l15][ks*32 + quad*8];
            #pragma unroll
            for (int nt = 0; nt < 2; ++nt)
                b[nt] = *(const v8bf*)&Bs[wc + 16*nt + l15][ks*32 + quad*8];
            #pragma unroll
            for (int mt = 0; mt < 4; ++mt)
                #pragma unroll
                for (int nt = 0; nt < 2; ++nt)
                    acc[mt][nt] = mfma16(a[mt], b[nt], acc[mt][nt]);
        }
        __syncthreads();
    }
#undef LOADG
#undef STORELDS

    #pragma unroll
    for (int mt = 0; mt < 4; ++mt) {
        #pragma unroll
        for (int nt = 0; nt < 2; ++nt) {
            int col = n0 + wc + 16*nt + l15;
            float bias = bf2f(bo[col]);
            #pragma unroll
            for (int reg = 0; reg < 4; ++reg) {
                int row = row0 + wr + 16*mt + quad*4 + reg;
                float val = acc[mt][nt][reg] + bias;
                if (is_f32) ((float*)outp)[(size_t)row * DMODEL + col] = val;
                else        ((u16*)outp)[(size_t)row * DMODEL + col]   = f2bf(val);
            }
        }
    }
}

extern "C" void kernel_launch(void* const* d_in, const int* in_sizes, int n_in,
                              void* d_out, int out_size, void* d_ws, size_t ws_size,
                              hipStream_t stream) {
    u16* ws = (u16*)d_ws;
    u16* canon = ws;
    u16* qws = ws + W_Q;
    u16* kws = ws + W_K;
    u16* vws = ws + W_V;
    u16* ctxp = ws + W_CTX;
    float* ropec = (float*)(ws + W_CTX);          // transient (dead before attn writes ctx)
    float* ropes = ropec + SEQ * DH;
    const u16* hs_raw = (const u16*)d_in[0];

    conv_hs_bo<<<dim3(4097), 256, 0, stream>>>(d_in[0], d_in[5], canon);
    transp_all<<<dim3(32, 32, 5), 256, 0, stream>>>(d_in[1], d_in[2], d_in[3],
        d_in[4], canon, hs_raw, ropec, ropes);
    gemm_qkv<<<dim3(32, 24), 512, 0, stream>>>(canon + C_HS, canon + C_WQ,
        canon + C_WK, canon + C_WV, ropec, ropes, qws, kws, vws);
    attn<<<dim3(16, NH, 2), 256, 0, stream>>>(qws, kws, vws, ctxp);
    oproj<<<dim3(32, 16), 512, 0, stream>>>(ctxp, canon + C_WO, canon + C_BO, hs_raw, d_out);
}

// Round 18
// 323.262 us; speedup vs baseline: 1.0578x; 1.0142x over previous
//
#include <hip/hip_runtime.h>
#include <hip/hip_bf16.h>
#include <math.h>

#define DMODEL 2048
#define SEQ    2048
#define NH     32
#define NG     8
#define DH     64

typedef unsigned short u16;
typedef unsigned int u32;
using v8bf  = __attribute__((ext_vector_type(8))) __bf16;
using f32x4 = __attribute__((ext_vector_type(4))) float;

__device__ __forceinline__ float bf2f(u16 u) {
    unsigned int x = ((unsigned int)u) << 16;
    return __uint_as_float(x);
}
__device__ __forceinline__ u16 f2bf(float f) {
    unsigned int x = __float_as_uint(f);
    unsigned int r = (x + 0x7fffu + ((x >> 16) & 1u)) >> 16;
    return (u16)r;
}
// HW RNE convert (single v_cvt vs 4 int ops) — bit-identical to f2bf for normals.
__device__ __forceinline__ u16 f2bf_hw(float f) {
    __bf16 b = (__bf16)f;
    return __builtin_bit_cast(u16, b);
}
// Pack two floats to bf16x2 in a u32 (2 v_cvt + 1 v_lshl_or).
__device__ __forceinline__ u32 f2bf_pk(float lo, float hi) {
    return (u32)f2bf_hw(lo) | ((u32)f2bf_hw(hi) << 16);
}
__device__ __forceinline__ f32x4 mfma16(v8bf a, v8bf b, f32x4 c) {
    return __builtin_amdgcn_mfma_f32_16x16x32_bf16(a, b, c, 0, 0, 0);
}

#define LOG1E4_64 0.14391156509880297f
#define LOG2E     1.4426950408889634f

// ws layout (u16 element offsets). Weights TRANSPOSED [n][k].
#define C_HS   0u
#define C_WQ   8388608u
#define C_WK   12582912u
#define C_WV   13631488u
#define C_WO   14680064u
#define C_BO   18874368u
#define W_Q    18876416u   // [b,h][s][d]
#define W_K    27265024u   // [b,g][s][d]
#define W_V    29362176u   // [b,g][d][s]
#define W_CTX  31459328u   // transient RoPE table -> bf16 ctx

// ---------------------------------------------------------------------------
// Runtime input-dtype detection. nw = number of waves in the block.
// ---------------------------------------------------------------------------
__device__ __forceinline__ bool detect_is_f32(const u16* hsu, int tid, float* red, int nw)
{
    ushort4 a = *(const ushort4*)(hsu + tid * 8);
    ushort4 b = *(const ushort4*)(hsu + tid * 8 + 4);
    u16 vals[8] = {a.x, a.y, a.z, a.w, b.x, b.y, b.z, b.w};
    float mymax = 0.0f;
    #pragma unroll
    for (int e = 0; e < 8; ++e) {
        float av = fabsf(bf2f(vals[e]));
        if (!(av < 1.0e30f)) av = 1.0e30f;
        mymax = fmaxf(mymax, av);
    }
    #pragma unroll
    for (int off = 1; off < 64; off <<= 1)
        mymax = fmaxf(mymax, __shfl_xor(mymax, off, 64));
    if ((tid & 63) == 0) red[tid >> 6] = mymax;
    __syncthreads();
    float m = red[0];
    for (int i = 1; i < nw; ++i) m = fmaxf(m, red[i]);
    __syncthreads();
    return m > 1.0e6f;
}

// ---------------------------------------------------------------------------
// Prelude (single launch, grid (32,32,9)): merges R17's conv_hs_bo +
// transp_all. No data dependency between the pieces (transp reads RAW
// weights/hs; conv writes canon) -> safe to fuse; removes one launch gap
// and lets hs-convert blocks fill the transpose blocks' tail.
//   z=0..3 : Wq/Wk/Wv/Wo transpose-convert (K=2048)
//   z=4    : bid<512 RoPE table; bid==512 bo convert
//   z=5..8 : hs convert (4096 blocks x 2048 u16)
// All branches block-uniform; all output regions disjoint.
// ---------------------------------------------------------------------------
__global__ __launch_bounds__(256)
void prelude_all(const void* __restrict__ hs, const void* __restrict__ bo,
                 const void* __restrict__ Wq, const void* __restrict__ Wk,
                 const void* __restrict__ Wv, const void* __restrict__ Wo,
                 u16* __restrict__ canon, float* __restrict__ ropec,
                 float* __restrict__ ropes)
{
    __shared__ float red[4];
    __shared__ u16 Ts[64][68];
    const int tid = threadIdx.x;
    const int z = blockIdx.z;
    const u16* hs_orig = (const u16*)hs;

    if (z >= 5) {   // hs convert
        const bool is_f32 = detect_is_f32(hs_orig, tid, red, 4);
        unsigned int gbid = (unsigned int)(z - 5) * 1024u
                          + blockIdx.y * 32u + blockIdx.x;
        unsigned int g = (gbid * 256u + tid) * 8u;
        u16* dst = canon + C_HS + g;
        if (is_f32) {
            const float* f = (const float*)hs + g;
            float4 x = *(const float4*)f;
            float4 y = *(const float4*)(f + 4);
            ushort4 o0, o1;
            o0.x = f2bf(x.x); o0.y = f2bf(x.y); o0.z = f2bf(x.z); o0.w = f2bf(x.w);
            o1.x = f2bf(y.x); o1.y = f2bf(y.y); o1.z = f2bf(y.z); o1.w = f2bf(y.w);
            *(ushort4*)dst       = o0;
            *(ushort4*)(dst + 4) = o1;
        } else {
            const u16* u = (const u16*)hs + g;
            *(ushort4*)dst       = *(const ushort4*)u;
            *(ushort4*)(dst + 4) = *(const ushort4*)(u + 4);
        }
        return;
    }

    if (z == 4) {
        int bid = blockIdx.y * 32 + blockIdx.x;
        if (bid < 512) {            // RoPE table
            int idx = bid * 256 + tid;
            int sq = idx >> 6, d = idx & 63;
            float freq = expf(-(float)(d & ~1) * LOG1E4_64);
            float sn, cs;
            sincosf((float)sq * freq, &sn, &cs);
            ropec[idx] = cs; ropes[idx] = sn;
            return;
        }
        if (bid == 512) {           // bo convert (2048 u16 = 1 block)
            const bool is_f32 = detect_is_f32(hs_orig, tid, red, 4);
            unsigned int g = (unsigned int)tid * 8u;
            u16* dst = canon + C_BO + g;
            if (is_f32) {
                const float* f = (const float*)bo + g;
                float4 x = *(const float4*)f;
                float4 y = *(const float4*)(f + 4);
                ushort4 o0, o1;
                o0.x = f2bf(x.x); o0.y = f2bf(x.y); o0.z = f2bf(x.z); o0.w = f2bf(x.w);
                o1.x = f2bf(y.x); o1.y = f2bf(y.y); o1.z = f2bf(y.z); o1.w = f2bf(y.w);
                *(ushort4*)dst       = o0;
                *(ushort4*)(dst + 4) = o1;
            } else {
                const u16* u = (const u16*)bo + g;
                *(ushort4*)dst       = *(const ushort4*)u;
                *(ushort4*)(dst + 4) = *(const ushort4*)(u + 4);
            }
            return;
        }
        return;
    }

    // z = 0..3: weight transpose-convert
    const void* W; u16* dst; int N;
    if (z == 0)      { W = Wq; dst = canon + C_WQ; N = 2048; }
    else if (z == 1) { W = Wk; dst = canon + C_WK; N = 512;  }
    else if (z == 2) { W = Wv; dst = canon + C_WV; N = 512;  }
    else             { W = Wo; dst = canon + C_WO; N = 2048; }
    const int n0 = blockIdx.x * 64, k0 = blockIdx.y * 64;
    if (n0 >= N) return;
    const int K = 2048;

    const bool is_f32 = detect_is_f32(hs_orig, tid, red, 4);

    #pragma unroll
    for (int it = 0; it < 4; ++it) {
        int e  = tid + it * 256;
        int kr = e >> 4, n4 = (e & 15) << 2;
        if (is_f32) {
            const float* s = (const float*)W + (size_t)(k0 + kr) * N + n0 + n4;
            float4 x = *(const float4*)s;
            Ts[n4+0][kr] = f2bf(x.x); Ts[n4+1][kr] = f2bf(x.y);
            Ts[n4+2][kr] = f2bf(x.z); Ts[n4+3][kr] = f2bf(x.w);
        } else {
            ushort4 u = *(const ushort4*)((const u16*)W + (size_t)(k0 + kr) * N + n0 + n4);
            Ts[n4+0][kr] = u.x; Ts[n4+1][kr] = u.y;
            Ts[n4+2][kr] = u.z; Ts[n4+3][kr] = u.w;
        }
    }
    __syncthreads();
    #pragma unroll
    for (int it = 0; it < 4; ++it) {
        int e  = tid + it * 256;
        int nr = e >> 4, k4 = (e & 15) << 2;
        ushort4 u;
        u.x = Ts[nr][k4+0]; u.y = Ts[nr][k4+1];
        u.z = Ts[nr][k4+2]; u.w = Ts[nr][k4+3];
        *(ushort4*)(dst + (size_t)(n0 + nr) * K + k0 + k4) = u;
    }
}

// ---------------------------------------------------------------------------
// Kernel 1: QKV projection (MFMA) + RoPE epilogue. 128x128 tile, BK=64,
// 512 threads = 8 waves (2x4), 64x32 per wave, demand<128 register contract
// (R4/R5/R12: acc[4][4]@256thr spills regardless of launch-bounds hints).
// Reg-staged [128][72] pad + cross-barrier prefetch (R10: gload_lds worse).
// NO XCD swizzle (R15/R16: kernel-local win but pipeline-level loss).
// ---------------------------------------------------------------------------
__global__ __launch_bounds__(512, 4) __attribute__((amdgpu_waves_per_eu(4, 4)))
void gemm_qkv(const u16* __restrict__ hs, const u16* __restrict__ wqt,
              const u16* __restrict__ wkt, const u16* __restrict__ wvt,
              const float* __restrict__ ropec, const float* __restrict__ ropes,
              u16* __restrict__ qws, u16* __restrict__ kws, u16* __restrict__ vws)
{
    __shared__ __align__(16) u16 As[128][72];
    __shared__ __align__(16) u16 Bs[128][72];
    const int tid = threadIdx.x;
    const int w = tid >> 6, lane = tid & 63;
    const int l15 = lane & 15, quad = lane >> 4;
    const int wr = (w >> 2) * 64, wc = (w & 3) * 32;
    const int row0 = blockIdx.x * 128;
    const int n0   = blockIdx.y * 128;

    const u16* Wt; int nb, mode;
    if (n0 < 2048)      { Wt = wqt; nb = n0;        mode = 0; }
    else if (n0 < 2560) { Wt = wkt; nb = n0 - 2048; mode = 1; }
    else                { Wt = wvt; nb = n0 - 2560; mode = 2; }

    const int r0 = tid >> 3, c0 = (tid & 7) * 8;
    const u16* arow = hs + (size_t)(row0 + r0) * DMODEL + c0;
    const u16* brow = Wt + (size_t)(nb   + r0) * DMODEL + c0;

    f32x4 acc[4][2];
    #pragma unroll
    for (int mt = 0; mt < 4; ++mt)
        #pragma unroll
        for (int nt = 0; nt < 2; ++nt)
            acc[mt][nt] = (f32x4){0.f, 0.f, 0.f, 0.f};

    uint4 ra0, ra1, rb0, rb1;
#define LOADG(k0_) do {                                                       \
    ra0 = *(const uint4*)(arow + (k0_));                                      \
    ra1 = *(const uint4*)(arow + (size_t)64 * DMODEL + (k0_));                \
    rb0 = *(const uint4*)(brow + (k0_));                                      \
    rb1 = *(const uint4*)(brow + (size_t)64 * DMODEL + (k0_));                \
} while (0)
#define STORELDS() do {                                                       \
    *(uint4*)&As[r0][c0]      = ra0;                                          \
    *(uint4*)&As[r0 + 64][c0] = ra1;                                          \
    *(uint4*)&Bs[r0][c0]      = rb0;                                          \
    *(uint4*)&Bs[r0 + 64][c0] = rb1;                                          \
} while (0)

    LOADG(0);
    for (int k0 = 0; k0 < DMODEL; k0 += 64) {
        STORELDS();
        __syncthreads();
        if (k0 + 64 < DMODEL) LOADG(k0 + 64);
        #pragma unroll
        for (int ks = 0; ks < 2; ++ks) {
            v8bf a[4], b[2];
            #pragma unroll
            for (int mt = 0; mt < 4; ++mt)
                a[mt] = *(const v8bf*)&As[wr + 16*mt + l15][ks*32 + quad*8];
            #pragma unroll
            for (int nt = 0; nt < 2; ++nt)
                b[nt] = *(const v8bf*)&Bs[wc + 16*nt + l15][ks*32 + quad*8];
            #pragma unroll
            for (int mt = 0; mt < 4; ++mt)
                #pragma unroll
                for (int nt = 0; nt < 2; ++nt)
                    acc[mt][nt] = mfma16(a[mt], b[nt], acc[mt][nt]);
        }
        __syncthreads();
    }
#undef LOADG
#undef STORELDS

    #pragma unroll
    for (int mt = 0; mt < 4; ++mt) {
        #pragma unroll
        for (int nt = 0; nt < 2; ++nt) {
            int col  = n0 + wc + 16*nt + l15;
            int dcol = col & 63;
            #pragma unroll
            for (int reg = 0; reg < 4; ++reg) {
                int row = row0 + wr + 16*mt + quad*4 + reg;
                int b = row >> 11, s = row & (SEQ - 1);
                float val = acc[mt][nt][reg];
                if (mode < 2) {   // RoPE (pairs sit in adjacent lanes)
                    float c2 = ropec[(s << 6) + dcol];
                    float s2 = ropes[(s << 6) + dcol];
                    float partner = __shfl_xor(val, 1, 64);
                    val = (dcol & 1) ? (val * c2 + partner * s2)
                                     : (val * c2 - partner * s2);
                }
                if (mode == 0) {
                    int h = col >> 6;
                    qws[((size_t)((b*NH + h) * SEQ + s)) * DH + dcol] = f2bf_hw(val);
                } else if (mode == 1) {
                    int g = (col - 2048) >> 6;
                    kws[((size_t)((b*NG + g) * SEQ + s)) * DH + dcol] = f2bf_hw(val);
                } else {
                    int g = (col - 2560) >> 6;
                    vws[((size_t)((b*NG + g) * DH + dcol)) * SEQ + s] = f2bf_hw(val);
                }
            }
        }
    }
}

// ---------------------------------------------------------------------------
// Kernel 2: flash attention (R17-verified, unchanged). Two q-tiles per
// block; K/V staged once into LDS, 2-phase lockstep with next-tile prefetch;
// swapped QK^T (mfma(K,Q)); packed P-store; causal mask s_local > 16w+l15;
// l via ones-fragment MFMA appended to PV.
// ---------------------------------------------------------------------------
__global__ __launch_bounds__(256, 4)
void attn(const u16* __restrict__ qws, const u16* __restrict__ kws,
          const u16* __restrict__ vws, u16* __restrict__ ctx)
{
    __shared__ __align__(16) u16 Ks[64][72];      // K tile [s_local][d]
    __shared__ __align__(16) u16 Vs[64][72];      // V tile [d][s_local]
    __shared__ __align__(16) u16 Ps[4][16][72];   // wave-private P [q][s]
    const int tid = threadIdx.x;
    const int w = tid >> 6, lane = tid & 63;
    const int l15 = lane & 15, quad = lane >> 4;
    const int sr = tid >> 3;          // staging row 0..31 (+32 second pass)
    const int sc = (tid & 7) * 8;     // staging col (u16 units, 16B chunks)

    const int h = blockIdx.y, b = blockIdx.z;
    const int g = h >> 2;

    const float slope = exp2f(-0.25f * (float)(h + 1));
    const u16* kbase  = kws + (size_t)(b*NG + g) * SEQ * DH;
    const u16* vtbase = vws + (size_t)(b*NG + g) * DH * SEQ;   // [d][s]
    const u16* qhead  = qws + (size_t)(b*NH + h) * SEQ * DH;

    const float Ac = 0.125f * (LOG2E / 15.0f);
    const float Bc = -slope * 0.125f * (LOG2E / 15.0f);
    const float C3 = -60.0f * LOG2E;
    // swapped bias: q_local = 16w + l15, s_local = 16mt + 4quad + rg
    float bdw[4][4];
    #pragma unroll
    for (int mt = 0; mt < 4; ++mt)
        #pragma unroll
        for (int reg = 0; reg < 4; ++reg)
            bdw[mt][reg] = Bc * (float)((16*w + l15) - (16*mt + 4*quad + reg));

    // all-ones B fragment for the l-row MFMA
    v8bf vones;
    #pragma unroll
    for (int j = 0; j < 8; ++j) vones[j] = (__bf16)1.0f;

    uint4 rk0, rk1, rv0, rv1;   // in-flight staging registers (one K/V tile)

#define LOADG(kt_) do {                                                       \
    const u16* kp_ = kbase + (size_t)(kt_) * (64 * DH);                       \
    rk0 = *(const uint4*)(kp_ + sr * DH + sc);                                \
    rk1 = *(const uint4*)(kp_ + (sr + 32) * DH + sc);                         \
    const u16* vp_ = vtbase + (size_t)(kt_) * 64;                             \
    rv0 = *(const uint4*)(vp_ + (size_t)sr * SEQ + sc);                       \
    rv1 = *(const uint4*)(vp_ + (size_t)(sr + 32) * SEQ + sc);                \
} while (0)

#define STORELDS() do {                                                       \
    *(uint4*)&Ks[sr][sc]      = rk0;                                          \
    *(uint4*)&Ks[sr + 32][sc] = rk1;                                          \
    *(uint4*)&Vs[sr][sc]      = rv0;                                          \
    *(uint4*)&Vs[sr + 32][sc] = rv1;                                          \
} while (0)

#define COMPUTE(kt_, DIAGC) do {                                              \
    f32x4 sacc_[4];                                                           \
    _Pragma("unroll")                                                         \
    for (int mt_ = 0; mt_ < 4; ++mt_) sacc_[mt_] = (f32x4){0.f,0.f,0.f,0.f};  \
    _Pragma("unroll")                                                         \
    for (int ks_ = 0; ks_ < 2; ++ks_)                                         \
        _Pragma("unroll")                                                     \
        for (int mt_ = 0; mt_ < 4; ++mt_) {                                   \
            v8bf kf_ = *(const v8bf*)&Ks[16*mt_ + l15][ks_*32 + quad*8];      \
            sacc_[mt_] = mfma16(kf_, qa[ks_], sacc_[mt_]);                    \
        }                                                                     \
    const float tb_ = Bc * (float)(q0 - (kt_) * 64);                          \
    _Pragma("unroll")                                                         \
    for (int mt_ = 0; mt_ < 4; ++mt_) {                                       \
        float pv_[4];                                                         \
        _Pragma("unroll")                                                     \
        for (int rg_ = 0; rg_ < 4; ++rg_) {                                   \
            float arg_ = fmaf(sacc_[mt_][rg_], Ac, bdw[mt_][rg_] + tb_);      \
            float wv_  = __builtin_amdgcn_exp2f(arg_);                        \
            float rr_  = __builtin_amdgcn_rcpf(wv_ + 1.0f);                   \
            float p_   = __builtin_amdgcn_exp2f(rr_ * C3);                    \
            if (DIAGC && (16*mt_ + 4*quad + rg_) > (16*w + l15)) p_ = 0.0f;   \
            pv_[rg_] = p_;                                                    \
        }                                                                     \
        uint2 pk_;                                                            \
        pk_.x = f2bf_pk(pv_[0], pv_[1]);                                      \
        pk_.y = f2bf_pk(pv_[2], pv_[3]);                                      \
        *(uint2*)&Ps[w][l15][16*mt_ + quad*4] = pk_;                          \
    }                                                                         \
    _Pragma("unroll")                                                         \
    for (int ks_ = 0; ks_ < 2; ++ks_) {                                       \
        v8bf pa_ = *(const v8bf*)&Ps[w][l15][ks_*32 + quad*8];                \
        _Pragma("unroll")                                                     \
        for (int dt_ = 0; dt_ < 4; ++dt_) {                                   \
            v8bf vf_ = *(const v8bf*)&Vs[16*dt_ + l15][ks_*32 + quad*8];      \
            o[dt_] = mfma16(pa_, vf_, o[dt_]);                                \
        }                                                                     \
        lacc = mfma16(pa_, vones, lacc);                                      \
    }                                                                         \
} while (0)

    #pragma unroll 1
    for (int half = 0; half < 2; ++half) {
        const int qt = half ? 31 - (int)blockIdx.x : (int)blockIdx.x;
        const int q0 = qt * 64;

        // Q frags in registers: rows q0+16w+l15 (valid as A or B operand)
        const u16* qrow = qhead + (size_t)(q0 + 16*w + l15) * DH;
        v8bf qa[2];
        qa[0] = *(const v8bf*)(qrow + 0*32 + quad*8);
        qa[1] = *(const v8bf*)(qrow + 1*32 + quad*8);

        f32x4 o[4];
        #pragma unroll
        for (int dt = 0; dt < 4; ++dt) o[dt] = (f32x4){0.f, 0.f, 0.f, 0.f};
        f32x4 lacc = (f32x4){0.f, 0.f, 0.f, 0.f};   // l[q=quad*4+reg], any col

        LOADG(0);
        for (int kt = 0; kt < qt; ++kt) {
            STORELDS();
            __syncthreads();
            LOADG(kt + 1);          // prefetch next tile while computing this one
            COMPUTE(kt, 0);
            __syncthreads();
        }
        STORELDS();                 // diag tile
        __syncthreads();
        COMPUTE(qt, 1);
        __syncthreads();

        // epilogue: l already in lacc[reg] (ones-MFMA) — no shuffles needed
        #pragma unroll
        for (int reg = 0; reg < 4; ++reg) {
            float linv = __builtin_amdgcn_rcpf(lacc[reg]);
            int s = q0 + 16*w + quad*4 + reg;
            u16* crow = ctx + (size_t)(b*SEQ + s) * DMODEL + h*64 + l15;
            #pragma unroll
            for (int dt = 0; dt < 4; ++dt)
                crow[16*dt] = f2bf_hw(o[dt][reg] * linv);
        }
    }
#undef LOADG
#undef STORELDS
#undef COMPUTE
}

// ---------------------------------------------------------------------------
// Kernel 3: out = ctx @ Wo + bo. Reg-staged 512-thread structure (R17
// config, no swizzle). LAUNCH WITH 512 THREADS.
// ---------------------------------------------------------------------------
__global__ __launch_bounds__(512, 4) __attribute__((amdgpu_waves_per_eu(4, 4)))
void oproj(const u16* __restrict__ ctx, const u16* __restrict__ wot,
           const u16* __restrict__ bo, const u16* __restrict__ hs_orig,
           void* __restrict__ outp)
{
    __shared__ float red[8];
    __shared__ __align__(16) u16 As[128][72];
    __shared__ __align__(16) u16 Bs[128][72];
    const int tid = threadIdx.x;
    const bool is_f32 = detect_is_f32(hs_orig, tid, red, 8);
    const int w = tid >> 6, lane = tid & 63;
    const int l15 = lane & 15, quad = lane >> 4;
    const int wr = (w >> 2) * 64, wc = (w & 3) * 32;
    const int row0 = blockIdx.x * 128;
    const int n0   = blockIdx.y * 128;

    const int r0 = tid >> 3, c0 = (tid & 7) * 8;
    const u16* arow = ctx + (size_t)(row0 + r0) * DMODEL + c0;
    const u16* brow = wot + (size_t)(n0   + r0) * DMODEL + c0;

    f32x4 acc[4][2];
    #pragma unroll
    for (int mt = 0; mt < 4; ++mt)
        #pragma unroll
        for (int nt = 0; nt < 2; ++nt)
            acc[mt][nt] = (f32x4){0.f, 0.f, 0.f, 0.f};

    uint4 ra0, ra1, rb0, rb1;
#define LOADG(k0_) do {                                                       \
    ra0 = *(const uint4*)(arow + (k0_));                                      \
    ra1 = *(const uint4*)(arow + (size_t)64 * DMODEL + (k0_));                \
    rb0 = *(const uint4*)(brow + (k0_));                                      \
    rb1 = *(const uint4*)(brow + (size_t)64 * DMODEL + (k0_));                \
} while (0)
#define STORELDS() do {                                                       \
    *(uint4*)&As[r0][c0]      = ra0;                                          \
    *(uint4*)&As[r0 + 64][c0] = ra1;                                          \
    *(uint4*)&Bs[r0][c0]      = rb0;                                          \
    *(uint4*)&Bs[r0 + 64][c0] = rb1;                                          \
} while (0)

    LOADG(0);
    for (int k0 = 0; k0 < DMODEL; k0 += 64) {
        STORELDS();
        __syncthreads();
        if (k0 + 64 < DMODEL) LOADG(k0 + 64);
        #pragma unroll
        for (int ks = 0; ks < 2; ++ks) {
            v8bf a[4], b[2];
            #pragma unroll
            for (int mt = 0; mt < 4; ++mt)
                a[mt] = *(const v8bf*)&As[wr + 16*mt + l15][ks*32 + quad*8];
            #pragma unroll
            for (int nt = 0; nt < 2; ++nt)
                b[nt] = *(const v8bf*)&Bs[wc + 16*nt + l15][ks*32 + quad*8];
            #pragma unroll
            for (int mt = 0; mt < 4; ++mt)
                #pragma unroll
                for (int nt = 0; nt < 2; ++nt)
                    acc[mt][nt] = mfma16(a[mt], b[nt], acc[mt][nt]);
        }
        __syncthreads();
    }
#undef LOADG
#undef STORELDS

    #pragma unroll
    for (int mt = 0; mt < 4; ++mt) {
        #pragma unroll
        for (int nt = 0; nt < 2; ++nt) {
            int col = n0 + wc + 16*nt + l15;
            float bias = bf2f(bo[col]);
            #pragma unroll
            for (int reg = 0; reg < 4; ++reg) {
                int row = row0 + wr + 16*mt + quad*4 + reg;
                float val = acc[mt][nt][reg] + bias;
                if (is_f32) ((float*)outp)[(size_t)row * DMODEL + col] = val;
                else        ((u16*)outp)[(size_t)row * DMODEL + col]   = f2bf(val);
            }
        }
    }
}

extern "C" void kernel_launch(void* const* d_in, const int* in_sizes, int n_in,
                              void* d_out, int out_size, void* d_ws, size_t ws_size,
                              hipStream_t stream) {
    u16* ws = (u16*)d_ws;
    u16* canon = ws;
    u16* qws = ws + W_Q;
    u16* kws = ws + W_K;
    u16* vws = ws + W_V;
    u16* ctxp = ws + W_CTX;
    float* ropec = (float*)(ws + W_CTX);          // transient (dead before attn writes ctx)
    float* ropes = ropec + SEQ * DH;
    const u16* hs_raw = (const u16*)d_in[0];

    prelude_all<<<dim3(32, 32, 9), 256, 0, stream>>>(d_in[0], d_in[5],
        d_in[1], d_in[2], d_in[3], d_in[4], canon, ropec, ropes);
    gemm_qkv<<<dim3(32, 24), 512, 0, stream>>>(canon + C_HS, canon + C_WQ,
        canon + C_WK, canon + C_WV, ropec, ropes, qws, kws, vws);
    attn<<<dim3(16, NH, 2), 256, 0, stream>>>(qws, kws, vws, ctxp);
    oproj<<<dim3(32, 16), 512, 0, stream>>>(ctxp, canon + C_WO, canon + C_BO, hs_raw, d_out);
}